// Round 6
// baseline (213.750 us; speedup 1.0000x reference)
//
#include <hip/hip_runtime.h>
#include <hip/hip_bf16.h>

#define DMODEL 1024
#define NHEAD 16
#define HDIM 64
#define CTXLEN 2048
#define BATCH 2
#define M_TOTAL (BATCH * CTXLEN)   // 4096

typedef unsigned short ushort_t;
typedef __attribute__((ext_vector_type(8))) short bf16x8;
typedef __attribute__((ext_vector_type(8))) unsigned short u16x8;
typedef __attribute__((ext_vector_type(4))) float f32x4;
typedef __attribute__((ext_vector_type(4))) unsigned short u16x4;

__device__ __forceinline__ unsigned short f32_bf16(float f) {
    unsigned u = __builtin_bit_cast(unsigned, f);
    u += 0x7FFFu + ((u >> 16) & 1u);
    return (unsigned short)(u >> 16);
}
__device__ __forceinline__ float bf16_f32(unsigned short h) {
    unsigned u = ((unsigned)h) << 16;
    return __builtin_bit_cast(float, u);
}
__device__ __forceinline__ float fast_exp2(float x) {
    return __builtin_amdgcn_exp2f(x);
}
__device__ __forceinline__ f32x4 mfma16(bf16x8 a, bf16x8 b, f32x4 c) {
    return __builtin_amdgcn_mfma_f32_16x16x32_bf16(a, b, c, 0, 0, 0);
}
__device__ __forceinline__ void gload_lds16(const ushort_t* g, ushort_t* l) {
    __builtin_amdgcn_global_load_lds(
        (const __attribute__((address_space(1))) void*)g,
        (__attribute__((address_space(3))) void*)l, 16, 0, 0);
}

// ---------------------------------------------------------------------------
// Elementwise converts
// ---------------------------------------------------------------------------
__global__ __launch_bounds__(256)
void split_hilo_f32(const float* __restrict__ src, ushort_t* __restrict__ h,
                    ushort_t* __restrict__ l, int n4) {
    for (int i = blockIdx.x * blockDim.x + threadIdx.x; i < n4;
         i += gridDim.x * blockDim.x) {
        const float4 v = reinterpret_cast<const float4*>(src)[i];
        const float f[4] = {v.x, v.y, v.z, v.w};
        u16x4 hi, lo;
        #pragma unroll
        for (int j = 0; j < 4; ++j) {
            const unsigned short hu = f32_bf16(f[j]);
            hi[j] = hu;
            lo[j] = f32_bf16(f[j] - bf16_f32(hu));
        }
        reinterpret_cast<u16x4*>(h)[i] = hi;
        reinterpret_cast<u16x4*>(l)[i] = lo;
    }
}

__global__ __launch_bounds__(256)
void conv_f32_bf16(const float* __restrict__ src, ushort_t* __restrict__ dst, int n4) {
    for (int i = blockIdx.x * blockDim.x + threadIdx.x; i < n4;
         i += gridDim.x * blockDim.x) {
        const float4 v = reinterpret_cast<const float4*>(src)[i];
        u16x4 o;
        o[0] = f32_bf16(v.x); o[1] = f32_bf16(v.y);
        o[2] = f32_bf16(v.z); o[3] = f32_bf16(v.w);
        reinterpret_cast<u16x4*>(dst)[i] = o;
    }
}

// ---------------------------------------------------------------------------
// bf16 MFMA GEMM (NT), 128x128 tile, BK=32, 4 waves.
// SPLIT: 3-term hi/lo product. QKV_EPI: epilogue writes q/k (hi/lo) or v
// arrays per section of col_base+col; else fp32 C + bias.
// ---------------------------------------------------------------------------
template<bool SPLIT, bool QKV_EPI>
__global__ __launch_bounds__(256)
void gemm_bf16_nt(const ushort_t* __restrict__ Ah, const ushort_t* __restrict__ Al,
                  const ushort_t* __restrict__ Bh, const ushort_t* __restrict__ Bl,
                  const float* __restrict__ bias, float* __restrict__ C,
                  ushort_t* __restrict__ qh, ushort_t* __restrict__ ql,
                  ushort_t* __restrict__ kh, ushort_t* __restrict__ kl,
                  ushort_t* __restrict__ vb,
                  int M, int N, int K, int col_base) {
    constexpr int NB = SPLIT ? 4 : 2;
    constexpr int IAH = 0, IAL = 1, IBH = SPLIT ? 2 : 1, IBL = 3;
    __shared__ ushort_t lds[NB * 4096];

    const int tid  = threadIdx.x;
    const int lane = tid & 63;
    const int wave = tid >> 6;
    const int lc   = lane & 15;
    const int lg   = lane >> 4;
    const int wr   = wave >> 1;
    const int wc   = wave & 1;
    const int row0 = blockIdx.y * 128;
    const int col0 = blockIdx.x * 128;

    const int c0 = tid, c1 = 256 + tid;
    const int r0 = c0 >> 2, l0 = (c0 & 3) ^ ((c0 >> 3) & 3);
    const int r1 = c1 >> 2, l1 = (c1 & 3) ^ ((c1 >> 3) & 3);
    const size_t gaoff0 = (size_t)(row0 + r0) * K + l0 * 8;
    const size_t gaoff1 = (size_t)(row0 + r1) * K + l1 * 8;
    const size_t gboff0 = (size_t)(col0 + r0) * K + l0 * 8;
    const size_t gboff1 = (size_t)(col0 + r1) * K + l1 * 8;
    const int ld0 = c0 * 8, ld1 = c1 * 8;

    int aoff[4], boff[4];
    #pragma unroll
    for (int m = 0; m < 4; ++m) {
        const int ra = wr * 64 + m * 16 + lc;
        aoff[m] = ra * 32 + ((lg ^ ((ra >> 1) & 3)) * 8);
        const int rb = wc * 64 + m * 16 + lc;
        boff[m] = rb * 32 + ((lg ^ ((rb >> 1) & 3)) * 8);
    }

    f32x4 acc[4][4];
    const f32x4 zero4 = {0.f, 0.f, 0.f, 0.f};
    #pragma unroll
    for (int m = 0; m < 4; ++m)
        #pragma unroll
        for (int n = 0; n < 4; ++n) acc[m][n] = zero4;

    const int NT = K >> 5;

    auto stage = [&](int kt) {
        const int ko = kt * 32;
        gload_lds16(Ah + gaoff0 + ko, &lds[IAH * 4096 + ld0]);
        gload_lds16(Ah + gaoff1 + ko, &lds[IAH * 4096 + ld1]);
        if (SPLIT) {
            gload_lds16(Al + gaoff0 + ko, &lds[IAL * 4096 + ld0]);
            gload_lds16(Al + gaoff1 + ko, &lds[IAL * 4096 + ld1]);
        }
        gload_lds16(Bh + gboff0 + ko, &lds[IBH * 4096 + ld0]);
        gload_lds16(Bh + gboff1 + ko, &lds[IBH * 4096 + ld1]);
        if (SPLIT) {
            gload_lds16(Bl + gboff0 + ko, &lds[IBL * 4096 + ld0]);
            gload_lds16(Bl + gboff1 + ko, &lds[IBL * 4096 + ld1]);
        }
    };

    stage(0);
    for (int kt = 0; kt < NT; ++kt) {
        __syncthreads();
        bf16x8 fah[4], fbh[4], fal[4], fbl[4];
        #pragma unroll
        for (int m = 0; m < 4; ++m) {
            fah[m] = *reinterpret_cast<const bf16x8*>(&lds[IAH * 4096 + aoff[m]]);
            fbh[m] = *reinterpret_cast<const bf16x8*>(&lds[IBH * 4096 + boff[m]]);
            if (SPLIT) {
                fal[m] = *reinterpret_cast<const bf16x8*>(&lds[IAL * 4096 + aoff[m]]);
                fbl[m] = *reinterpret_cast<const bf16x8*>(&lds[IBL * 4096 + boff[m]]);
            }
        }
        __syncthreads();
        if (kt + 1 < NT) stage(kt + 1);
        __builtin_amdgcn_s_setprio(1);
        #pragma unroll
        for (int m = 0; m < 4; ++m)
            #pragma unroll
            for (int n = 0; n < 4; ++n) {
                f32x4 t = acc[m][n];
                t = mfma16(fah[m], fbh[n], t);
                if (SPLIT) {
                    t = mfma16(fal[m], fbh[n], t);
                    t = mfma16(fah[m], fbl[n], t);
                }
                acc[m][n] = t;
            }
        __builtin_amdgcn_s_setprio(0);
    }

    if (!QKV_EPI) {
        #pragma unroll
        for (int m = 0; m < 4; ++m)
            #pragma unroll
            for (int i = 0; i < 4; ++i) {
                const int r = row0 + wr * 64 + m * 16 + lg * 4 + i;
                #pragma unroll
                for (int n = 0; n < 4; ++n) {
                    const int c = col0 + wc * 64 + n * 16 + lc;
                    C[(size_t)r * N + c] = acc[m][n][i] + bias[c];
                }
            }
    } else {
        #pragma unroll
        for (int m = 0; m < 4; ++m)
            #pragma unroll
            for (int i = 0; i < 4; ++i) {
                const int r = row0 + wr * 64 + m * 16 + lg * 4 + i;
                const int bb = r >> 11;
                const int t  = r & 2047;
                #pragma unroll
                for (int n = 0; n < 4; ++n) {
                    const int cg = col_base + col0 + wc * 64 + n * 16 + lc;
                    const int sec = cg >> 10;            // 0=q, 1=k, 2=v
                    const int ch  = cg & 1023;
                    const int hh  = ch >> 6;
                    const int d   = ch & 63;
                    const size_t off = (((size_t)(bb * NHEAD + hh)) * CTXLEN + t) * HDIM + d;
                    const float v = acc[m][n][i];
                    if (sec == 0) {
                        const unsigned short hu = f32_bf16(v);
                        qh[off] = hu;
                        ql[off] = f32_bf16(v - bf16_f32(hu));
                    } else if (sec == 1) {
                        const unsigned short hu = f32_bf16(v);
                        kh[off] = hu;
                        kl[off] = f32_bf16(v - bf16_f32(hu));
                    } else {
                        vb[off] = f32_bf16(v);
                    }
                }
            }
    }
}

// ---------------------------------------------------------------------------
// vb [bh][t][d] -> vt [bh][d][t] (bf16), 64x64 tiles via LDS.
// ---------------------------------------------------------------------------
__global__ __launch_bounds__(256)
void transpose_v(const ushort_t* __restrict__ vb, ushort_t* __restrict__ vt) {
    __shared__ ushort_t T[64][66];
    const int tt = blockIdx.x;
    const int bh = blockIdx.y;
    const int tid = threadIdx.x;
    const int r  = tid >> 2;
    const int c0 = (tid & 3) * 16;

    const ushort_t* src = vb + ((size_t)bh * CTXLEN + tt * 64) * HDIM;
    #pragma unroll
    for (int half = 0; half < 2; ++half) {
        const u16x8 v = *reinterpret_cast<const u16x8*>(&src[(size_t)r * HDIM + c0 + half * 8]);
        #pragma unroll
        for (int j = 0; j < 8; ++j) T[r][c0 + half * 8 + j] = v[j];
    }
    __syncthreads();
    ushort_t* dst = vt + ((size_t)bh * HDIM + r) * CTXLEN + tt * 64 + c0;
    u16x8 o0, o1;
    #pragma unroll
    for (int j = 0; j < 8; ++j) { o0[j] = T[c0 + j][r]; o1[j] = T[c0 + 8 + j][r]; }
    *reinterpret_cast<u16x8*>(&dst[0]) = o0;
    *reinterpret_cast<u16x8*>(&dst[8]) = o1;
}

// ---------------------------------------------------------------------------
// Flash causal attention v3. LDS = 40960 B exactly -> 4 blocks/CU (50% occ cap).
//   KH dbuf (staged, swizzled), VT dbuf (staged, swizzled),
//   K-lo fragments straight from global (L1-broadcast across waves),
//   Ps XOR-swizzled (no pad).
// Grid 1024: bh = id&31, qb = 31 - id>>5 (LPT-ish under round-robin).
// ---------------------------------------------------------------------------
#define SCALE_LOG2 11.5415603271f   // 8 * log2(e)

__global__ __launch_bounds__(256)
void attn_fwd3(const ushort_t* __restrict__ qh, const ushort_t* __restrict__ ql,
               const ushort_t* __restrict__ kh, const ushort_t* __restrict__ kl,
               const ushort_t* __restrict__ vt, ushort_t* __restrict__ yb) {
    __shared__ ushort_t KH[2][4096];
    __shared__ ushort_t VT[2][4096];
    __shared__ ushort_t Ps[4][16][64];

    const int id = blockIdx.x;
    const int bh = id & 31;
    const int qb = 31 - (id >> 5);
    const int b  = bh >> 4;

    const int tid  = threadIdx.x;
    const int wave = tid >> 6;
    const int lane = tid & 63;
    const int lc   = lane & 15;
    const int lg   = lane >> 4;

    const ushort_t* khb = kh + (size_t)bh * CTXLEN * HDIM;
    const ushort_t* klb = kl + (size_t)bh * CTXLEN * HDIM;
    const ushort_t* vtb = vt + (size_t)bh * HDIM * CTXLEN;

    // staging: chunk c in [0,512): row r=c>>3, lds slot s=c&7, global slot s^(r&7)
    const int cA = tid, cB = 256 + tid;
    const int rA = cA >> 3, sgA = (cA & 7) ^ (rA & 7);
    const int rB = cB >> 3, sgB = (cB & 7) ^ (rB & 7);

    auto stage = [&](int kb, int buf) {
        const size_t koff = (size_t)(kb * 64);
        gload_lds16(khb + (koff + rA) * HDIM + sgA * 8, &KH[buf][cA * 8]);
        gload_lds16(khb + (koff + rB) * HDIM + sgB * 8, &KH[buf][cB * 8]);
        gload_lds16(vtb + (size_t)rA * CTXLEN + kb * 64 + sgA * 8, &VT[buf][cA * 8]);
        gload_lds16(vtb + (size_t)rB * CTXLEN + kb * 64 + sgB * 8, &VT[buf][cB * 8]);
    };

    // Q fragments from global (hi/lo)
    const size_t qrow = (size_t)bh * CTXLEN + qb * 64 + wave * 16 + lc;
    bf16x8 qfh[2], qfl[2];
    #pragma unroll
    for (int ds = 0; ds < 2; ++ds) {
        qfh[ds] = *reinterpret_cast<const bf16x8*>(&qh[qrow * HDIM + ds * 32 + lg * 8]);
        qfl[ds] = *reinterpret_cast<const bf16x8*>(&ql[qrow * HDIM + ds * 32 + lg * 8]);
    }

    const f32x4 zero4 = {0.f, 0.f, 0.f, 0.f};
    f32x4 yacc[4];
    #pragma unroll
    for (int t = 0; t < 4; ++t) yacc[t] = zero4;
    float m_i[4] = {-1e30f, -1e30f, -1e30f, -1e30f};
    float l_i[4] = {0.f, 0.f, 0.f, 0.f};

    stage(0, 0);
    __syncthreads();

    int cur = 0;
    for (int kb = 0; kb <= qb; ++kb) {
        if (kb < qb) stage(kb + 1, cur ^ 1);

        // ---- K-lo fragments straight from global (same addr across waves -> L1) ----
        bf16x8 kfl[4][2];
        #pragma unroll
        for (int tc = 0; tc < 4; ++tc) {
            const size_t krow = (size_t)(kb * 64 + tc * 16 + lc);
            #pragma unroll
            for (int ds = 0; ds < 2; ++ds)
                kfl[tc][ds] = *reinterpret_cast<const bf16x8*>(&klb[krow * HDIM + ds * 32 + lg * 8]);
        }
        // ---- K-hi fragments from LDS (swizzled) ----
        bf16x8 kfh[4][2];
        #pragma unroll
        for (int tc = 0; tc < 4; ++tc) {
            const int rk = tc * 16 + lc;
            #pragma unroll
            for (int ds = 0; ds < 2; ++ds) {
                const int a = rk * 64 + (((ds * 4 + lg) ^ (rk & 7)) * 8);
                kfh[tc][ds] = *reinterpret_cast<const bf16x8*>(&KH[cur][a]);
            }
        }

        // ---- S = Q K^T (3-term hi/lo) ----
        f32x4 sacc[4];
        #pragma unroll
        for (int t = 0; t < 4; ++t) sacc[t] = zero4;
        __builtin_amdgcn_s_setprio(1);
        #pragma unroll
        for (int tc = 0; tc < 4; ++tc)
            #pragma unroll
            for (int ds = 0; ds < 2; ++ds) {
                sacc[tc] = mfma16(qfh[ds], kfh[tc][ds], sacc[tc]);
                sacc[tc] = mfma16(qfl[ds], kfh[tc][ds], sacc[tc]);
                sacc[tc] = mfma16(qfh[ds], kfl[tc][ds], sacc[tc]);
            }
        __builtin_amdgcn_s_setprio(0);

        // ---- mask + online softmax (base-2) ----
        const bool diag = (kb == qb);
        float sv[4][4];
        #pragma unroll
        for (int tc = 0; tc < 4; ++tc)
            #pragma unroll
            for (int i = 0; i < 4; ++i) {
                float u = sacc[tc][i] * SCALE_LOG2;
                if (diag && (tc * 16 + lc) > (wave * 16 + lg * 4 + i)) u = -1e30f;
                sv[tc][i] = u;
            }
        #pragma unroll
        for (int i = 0; i < 4; ++i) {
            float mx = fmaxf(fmaxf(sv[0][i], sv[1][i]), fmaxf(sv[2][i], sv[3][i]));
            mx = fmaxf(mx, __shfl_xor(mx, 1));
            mx = fmaxf(mx, __shfl_xor(mx, 2));
            mx = fmaxf(mx, __shfl_xor(mx, 4));
            mx = fmaxf(mx, __shfl_xor(mx, 8));
            const float mnew = fmaxf(m_i[i], mx);
            const float corr = fast_exp2(m_i[i] - mnew);
            float psum = 0.f;
            #pragma unroll
            for (int tc = 0; tc < 4; ++tc) {
                const float p = fast_exp2(sv[tc][i] - mnew);
                sv[tc][i] = p;
                psum += p;
            }
            psum += __shfl_xor(psum, 1);
            psum += __shfl_xor(psum, 2);
            psum += __shfl_xor(psum, 4);
            psum += __shfl_xor(psum, 8);
            l_i[i] = l_i[i] * corr + psum;
            m_i[i] = mnew;
            #pragma unroll
            for (int t = 0; t < 4; ++t) yacc[t][i] *= corr;
        }

        // ---- P -> LDS (wave-private, XOR-swizzled) ----
        #pragma unroll
        for (int tc = 0; tc < 4; ++tc)
            #pragma unroll
            for (int i = 0; i < 4; ++i) {
                const int row = lg * 4 + i;
                const int e   = tc * 16 + lc;
                const int se  = (((e >> 3) ^ (row & 7)) << 3) | (e & 7);
                Ps[wave][row][se] = f32_bf16(sv[tc][i]);
            }

        // ---- y += P V ----
        bf16x8 pa[2];
        #pragma unroll
        for (int ks = 0; ks < 2; ++ks) {
            const int sl = ((ks * 4 + lg) ^ (lc & 7)) << 3;
            pa[ks] = *reinterpret_cast<const bf16x8*>(&Ps[wave][lc][sl]);
        }
        __builtin_amdgcn_s_setprio(1);
        #pragma unroll
        for (int t = 0; t < 4; ++t) {
            const int rv = t * 16 + lc;
            #pragma unroll
            for (int ks = 0; ks < 2; ++ks) {
                const int a = rv * 64 + (((ks * 4 + lg) ^ (rv & 7)) * 8);
                const bf16x8 vf = *reinterpret_cast<const bf16x8*>(&VT[cur][a]);
                yacc[t] = mfma16(pa[ks], vf, yacc[t]);
            }
        }
        __builtin_amdgcn_s_setprio(0);

        __syncthreads();
        cur ^= 1;
    }

    float inv[4];
    #pragma unroll
    for (int i = 0; i < 4; ++i) inv[i] = 1.0f / l_i[i];
    ushort_t* yrow0 = yb + (size_t)(b * CTXLEN + qb * 64 + wave * 16 + lg * 4) * DMODEL
                      + (bh & 15) * HDIM;
    #pragma unroll
    for (int t = 0; t < 4; ++t)
        #pragma unroll
        for (int i = 0; i < 4; ++i)
            yrow0[(size_t)i * DMODEL + t * 16 + lc] = f32_bf16(yacc[t][i] * inv[i]);
}

// ---------------------------------------------------------------------------
extern "C" void kernel_launch(void* const* d_in, const int* in_sizes, int n_in,
                              void* d_out, int out_size, void* d_ws, size_t ws_size,
                              hipStream_t stream) {
    const float* x      = (const float*)d_in[0];
    const float* w_qkv  = (const float*)d_in[1];
    const float* w_proj = (const float*)d_in[2];
    const float* b_proj = (const float*)d_in[3];
    float* out = (float*)d_out;

    char* ws = (char*)d_ws;
    ushort_t* wh  = (ushort_t*)(ws);
    ushort_t* wl  = (ushort_t*)(ws + 6291456);
    ushort_t* xh  = (ushort_t*)(ws + 12582912);
    ushort_t* xl  = (ushort_t*)(ws + 20971520);
    ushort_t* qh  = (ushort_t*)(ws + 29360128);
    ushort_t* ql  = (ushort_t*)(ws + 37748736);
    ushort_t* kh  = (ushort_t*)(ws + 46137344);
    ushort_t* kl  = (ushort_t*)(ws + 54525952);
    ushort_t* vb  = (ushort_t*)(ws + 62914560);
    ushort_t* vt  = (ushort_t*)(ws + 71303168);
    ushort_t* yb  = xh;
    ushort_t* wph = xl;

    const dim3 blk(256);

    split_hilo_f32<<<dim3(2048), blk, 0, stream>>>(x, xh, xl, M_TOTAL * DMODEL / 4);
    split_hilo_f32<<<dim3(2048), blk, 0, stream>>>(w_qkv, wh, wl, 3 * DMODEL * DMODEL / 4);

    // qkv GEMM A: q,k columns (N=2048), 3-term hi/lo
    gemm_bf16_nt<true, true><<<dim3(2048 / 128, M_TOTAL / 128), blk, 0, stream>>>(
        xh, xl, wh, wl, nullptr, nullptr, qh, ql, kh, kl, vb,
        M_TOTAL, 3 * DMODEL, DMODEL, 0);

    // qkv GEMM B: v columns (N=1024), 1-term bf16
    gemm_bf16_nt<false, true><<<dim3(1024 / 128, M_TOTAL / 128), blk, 0, stream>>>(
        xh, nullptr, wh + (size_t)2048 * DMODEL, nullptr, nullptr, nullptr,
        qh, ql, kh, kl, vb,
        M_TOTAL, 3 * DMODEL, DMODEL, 2048);

    conv_f32_bf16<<<dim3(1024), blk, 0, stream>>>(w_proj, wph, DMODEL * DMODEL / 4);

    transpose_v<<<dim3(CTXLEN / 64, BATCH * NHEAD), blk, 0, stream>>>(vb, vt);

    attn_fwd3<<<dim3(1024), blk, 0, stream>>>(qh, ql, kh, kl, vt, yb);

    gemm_bf16_nt<false, false><<<dim3(DMODEL / 128, M_TOTAL / 128), blk, 0, stream>>>(
        yb, nullptr, wph, nullptr, b_proj, out, nullptr, nullptr, nullptr, nullptr, nullptr,
        M_TOTAL, DMODEL, DMODEL, 0);
}

// Round 7
// 183.041 us; speedup vs baseline: 1.1678x; 1.1678x over previous
//
#include <hip/hip_runtime.h>
#include <hip/hip_bf16.h>

#define DMODEL 1024
#define NHEAD 16
#define HDIM 64
#define CTXLEN 2048
#define BATCH 2
#define M_TOTAL (BATCH * CTXLEN)   // 4096

typedef unsigned short ushort_t;
typedef __attribute__((ext_vector_type(8))) short bf16x8;
typedef __attribute__((ext_vector_type(8))) _Float16 f16x8;
typedef __attribute__((ext_vector_type(8))) unsigned short u16x8;
typedef __attribute__((ext_vector_type(4))) float f32x4;
typedef __attribute__((ext_vector_type(4))) unsigned short u16x4;

__device__ __forceinline__ unsigned short f32_bf16(float f) {
    unsigned u = __builtin_bit_cast(unsigned, f);
    u += 0x7FFFu + ((u >> 16) & 1u);
    return (unsigned short)(u >> 16);
}
__device__ __forceinline__ float bf16_f32(unsigned short h) {
    unsigned u = ((unsigned)h) << 16;
    return __builtin_bit_cast(float, u);
}
__device__ __forceinline__ unsigned short f32_f16(float f) {
    return __builtin_bit_cast(unsigned short, (_Float16)f);
}
__device__ __forceinline__ float fast_exp2(float x) {
    return __builtin_amdgcn_exp2f(x);
}
__device__ __forceinline__ f32x4 mfma16b(bf16x8 a, bf16x8 b, f32x4 c) {
    return __builtin_amdgcn_mfma_f32_16x16x32_bf16(a, b, c, 0, 0, 0);
}
__device__ __forceinline__ f32x4 mfma16f(f16x8 a, f16x8 b, f32x4 c) {
    return __builtin_amdgcn_mfma_f32_16x16x32_f16(a, b, c, 0, 0, 0);
}
__device__ __forceinline__ void gload_lds16(const ushort_t* g, ushort_t* l) {
    __builtin_amdgcn_global_load_lds(
        (const __attribute__((address_space(1))) void*)g,
        (__attribute__((address_space(3))) void*)l, 16, 0, 0);
}

// ---------------------------------------------------------------------------
// Elementwise converts
// ---------------------------------------------------------------------------
__global__ __launch_bounds__(256)
void split_hilo_f32(const float* __restrict__ src, ushort_t* __restrict__ h,
                    ushort_t* __restrict__ l, int n4) {
    for (int i = blockIdx.x * blockDim.x + threadIdx.x; i < n4;
         i += gridDim.x * blockDim.x) {
        const float4 v = reinterpret_cast<const float4*>(src)[i];
        const float f[4] = {v.x, v.y, v.z, v.w};
        u16x4 hi, lo;
        #pragma unroll
        for (int j = 0; j < 4; ++j) {
            const unsigned short hu = f32_bf16(f[j]);
            hi[j] = hu;
            lo[j] = f32_bf16(f[j] - bf16_f32(hu));
        }
        reinterpret_cast<u16x4*>(h)[i] = hi;
        reinterpret_cast<u16x4*>(l)[i] = lo;
    }
}

__global__ __launch_bounds__(256)
void conv_f32_f16(const float* __restrict__ src, ushort_t* __restrict__ dst, int n4) {
    for (int i = blockIdx.x * blockDim.x + threadIdx.x; i < n4;
         i += gridDim.x * blockDim.x) {
        const float4 v = reinterpret_cast<const float4*>(src)[i];
        u16x4 o;
        o[0] = f32_f16(v.x); o[1] = f32_f16(v.y);
        o[2] = f32_f16(v.z); o[3] = f32_f16(v.w);
        reinterpret_cast<u16x4*>(dst)[i] = o;
    }
}

// ---------------------------------------------------------------------------
// MFMA GEMM (NT), 128x128 tile, BK=32, 4 waves.
// SPLIT: bf16 3-term hi/lo product (A=Ah+Al, B=Bh+Bl).
// F16: operands are fp16 (single-term), uses f16 MFMA.
// QKV_EPI: epilogue writes fp16 q/k/v arrays per section of col_base+col;
// else fp32 C + bias.
// ---------------------------------------------------------------------------
template<bool SPLIT, bool F16, bool QKV_EPI>
__global__ __launch_bounds__(256)
void gemm_mfma_nt(const ushort_t* __restrict__ Ah, const ushort_t* __restrict__ Al,
                  const ushort_t* __restrict__ Bh, const ushort_t* __restrict__ Bl,
                  const float* __restrict__ bias, float* __restrict__ C,
                  ushort_t* __restrict__ qf, ushort_t* __restrict__ kf,
                  ushort_t* __restrict__ vb,
                  int M, int N, int K, int col_base) {
    constexpr int NB = SPLIT ? 4 : 2;
    constexpr int IAH = 0, IAL = 1, IBH = SPLIT ? 2 : 1, IBL = 3;
    __shared__ ushort_t lds[NB * 4096];

    const int tid  = threadIdx.x;
    const int lane = tid & 63;
    const int wave = tid >> 6;
    const int lc   = lane & 15;
    const int lg   = lane >> 4;
    const int wr   = wave >> 1;
    const int wc   = wave & 1;
    const int row0 = blockIdx.y * 128;
    const int col0 = blockIdx.x * 128;

    const int c0 = tid, c1 = 256 + tid;
    const int r0 = c0 >> 2, l0 = (c0 & 3) ^ ((c0 >> 3) & 3);
    const int r1 = c1 >> 2, l1 = (c1 & 3) ^ ((c1 >> 3) & 3);
    const size_t gaoff0 = (size_t)(row0 + r0) * K + l0 * 8;
    const size_t gaoff1 = (size_t)(row0 + r1) * K + l1 * 8;
    const size_t gboff0 = (size_t)(col0 + r0) * K + l0 * 8;
    const size_t gboff1 = (size_t)(col0 + r1) * K + l1 * 8;
    const int ld0 = c0 * 8, ld1 = c1 * 8;

    int aoff[4], boff[4];
    #pragma unroll
    for (int m = 0; m < 4; ++m) {
        const int ra = wr * 64 + m * 16 + lc;
        aoff[m] = ra * 32 + ((lg ^ ((ra >> 1) & 3)) * 8);
        const int rb = wc * 64 + m * 16 + lc;
        boff[m] = rb * 32 + ((lg ^ ((rb >> 1) & 3)) * 8);
    }

    f32x4 acc[4][4];
    const f32x4 zero4 = {0.f, 0.f, 0.f, 0.f};
    #pragma unroll
    for (int m = 0; m < 4; ++m)
        #pragma unroll
        for (int n = 0; n < 4; ++n) acc[m][n] = zero4;

    const int NT = K >> 5;

    auto stage = [&](int kt) {
        const int ko = kt * 32;
        gload_lds16(Ah + gaoff0 + ko, &lds[IAH * 4096 + ld0]);
        gload_lds16(Ah + gaoff1 + ko, &lds[IAH * 4096 + ld1]);
        if (SPLIT) {
            gload_lds16(Al + gaoff0 + ko, &lds[IAL * 4096 + ld0]);
            gload_lds16(Al + gaoff1 + ko, &lds[IAL * 4096 + ld1]);
        }
        gload_lds16(Bh + gboff0 + ko, &lds[IBH * 4096 + ld0]);
        gload_lds16(Bh + gboff1 + ko, &lds[IBH * 4096 + ld1]);
        if (SPLIT) {
            gload_lds16(Bl + gboff0 + ko, &lds[IBL * 4096 + ld0]);
            gload_lds16(Bl + gboff1 + ko, &lds[IBL * 4096 + ld1]);
        }
    };

    stage(0);
    for (int kt = 0; kt < NT; ++kt) {
        __syncthreads();
        bf16x8 fah[4], fbh[4], fal[4], fbl[4];
        #pragma unroll
        for (int m = 0; m < 4; ++m) {
            fah[m] = *reinterpret_cast<const bf16x8*>(&lds[IAH * 4096 + aoff[m]]);
            fbh[m] = *reinterpret_cast<const bf16x8*>(&lds[IBH * 4096 + boff[m]]);
            if (SPLIT) {
                fal[m] = *reinterpret_cast<const bf16x8*>(&lds[IAL * 4096 + aoff[m]]);
                fbl[m] = *reinterpret_cast<const bf16x8*>(&lds[IBL * 4096 + boff[m]]);
            }
        }
        __syncthreads();
        if (kt + 1 < NT) stage(kt + 1);
        #pragma unroll
        for (int m = 0; m < 4; ++m)
            #pragma unroll
            for (int n = 0; n < 4; ++n) {
                f32x4 t = acc[m][n];
                if (F16) {
                    t = mfma16f(__builtin_bit_cast(f16x8, fah[m]),
                                __builtin_bit_cast(f16x8, fbh[n]), t);
                } else {
                    t = mfma16b(fah[m], fbh[n], t);
                    if (SPLIT) {
                        t = mfma16b(fal[m], fbh[n], t);
                        t = mfma16b(fah[m], fbl[n], t);
                    }
                }
                acc[m][n] = t;
            }
    }

    if (!QKV_EPI) {
        #pragma unroll
        for (int m = 0; m < 4; ++m)
            #pragma unroll
            for (int i = 0; i < 4; ++i) {
                const int r = row0 + wr * 64 + m * 16 + lg * 4 + i;
                #pragma unroll
                for (int n = 0; n < 4; ++n) {
                    const int c = col0 + wc * 64 + n * 16 + lc;
                    C[(size_t)r * N + c] = acc[m][n][i] + bias[c];
                }
            }
    } else {
        #pragma unroll
        for (int m = 0; m < 4; ++m)
            #pragma unroll
            for (int i = 0; i < 4; ++i) {
                const int r = row0 + wr * 64 + m * 16 + lg * 4 + i;
                const int bb = r >> 11;
                const int t  = r & 2047;
                #pragma unroll
                for (int n = 0; n < 4; ++n) {
                    const int cg = col_base + col0 + wc * 64 + n * 16 + lc;
                    const int sec = cg >> 10;            // 0=q, 1=k, 2=v
                    const int ch  = cg & 1023;
                    const int hh  = ch >> 6;
                    const int d   = ch & 63;
                    const size_t off = (((size_t)(bb * NHEAD + hh)) * CTXLEN + t) * HDIM + d;
                    const unsigned short hv = f32_f16(acc[m][n][i]);
                    if (sec == 0)      qf[off] = hv;
                    else if (sec == 1) kf[off] = hv;
                    else               vb[off] = hv;
                }
            }
    }
}

// ---------------------------------------------------------------------------
// vb [bh][t][d] -> vt [bh][d][t] (16-bit payload), 64x64 tiles via LDS.
// ---------------------------------------------------------------------------
__global__ __launch_bounds__(256)
void transpose_v(const ushort_t* __restrict__ vb, ushort_t* __restrict__ vt) {
    __shared__ ushort_t T[64][66];
    const int tt = blockIdx.x;
    const int bh = blockIdx.y;
    const int tid = threadIdx.x;
    const int r  = tid >> 2;
    const int c0 = (tid & 3) * 16;

    const ushort_t* src = vb + ((size_t)bh * CTXLEN + tt * 64) * HDIM;
    #pragma unroll
    for (int half = 0; half < 2; ++half) {
        const u16x8 v = *reinterpret_cast<const u16x8*>(&src[(size_t)r * HDIM + c0 + half * 8]);
        #pragma unroll
        for (int j = 0; j < 8; ++j) T[r][c0 + half * 8 + j] = v[j];
    }
    __syncthreads();
    ushort_t* dst = vt + ((size_t)bh * HDIM + r) * CTXLEN + tt * 64 + c0;
    u16x8 o0, o1;
    #pragma unroll
    for (int j = 0; j < 8; ++j) { o0[j] = T[c0 + j][r]; o1[j] = T[c0 + 8 + j][r]; }
    *reinterpret_cast<u16x8*>(&dst[0]) = o0;
    *reinterpret_cast<u16x8*>(&dst[8]) = o1;
}

// ---------------------------------------------------------------------------
// Flash causal attention v4: fp16 single-term QK^T + fp16 PV.
// LDS = 40960 B exactly (KH dbuf + VT dbuf + Ps) -> 4 blocks/CU cap.
// Grid 1024: bh = id&31 (same head -> same XCD L2); qb balanced so every CU's
// 4 round-robin blocks total exactly 66 tile-steps.
// ---------------------------------------------------------------------------
#define SCALE_LOG2 11.5415603271f   // 8 * log2(e)

__global__ __launch_bounds__(256)
void attn_fwd4(const ushort_t* __restrict__ qf, const ushort_t* __restrict__ kf,
               const ushort_t* __restrict__ vt, ushort_t* __restrict__ yb) {
    __shared__ ushort_t KH[2][4096];
    __shared__ ushort_t VT[2][4096];
    __shared__ ushort_t Ps[4][16][64];

    const int id = blockIdx.x;
    const int bh = id & 31;
    const int g  = (id >> 5) & 7;
    const int j  = id >> 8;
    const int qb = 8 * j + ((j & 1) ? g : 7 - g);
    const int b  = bh >> 4;

    const int tid  = threadIdx.x;
    const int wave = tid >> 6;
    const int lane = tid & 63;
    const int lc   = lane & 15;
    const int lg   = lane >> 4;

    const ushort_t* kfb = kf + (size_t)bh * CTXLEN * HDIM;
    const ushort_t* vtb = vt + (size_t)bh * HDIM * CTXLEN;

    // staging: chunk c in [0,512): row r=c>>3, lds slot s=c&7, global slot s^(r&7)
    const int cA = tid, cB = 256 + tid;
    const int rA = cA >> 3, sgA = (cA & 7) ^ (rA & 7);
    const int rB = cB >> 3, sgB = (cB & 7) ^ (rB & 7);

    auto stage = [&](int kb, int buf) {
        const size_t koff = (size_t)(kb * 64);
        gload_lds16(kfb + (koff + rA) * HDIM + sgA * 8, &KH[buf][cA * 8]);
        gload_lds16(kfb + (koff + rB) * HDIM + sgB * 8, &KH[buf][cB * 8]);
        gload_lds16(vtb + (size_t)rA * CTXLEN + kb * 64 + sgA * 8, &VT[buf][cA * 8]);
        gload_lds16(vtb + (size_t)rB * CTXLEN + kb * 64 + sgB * 8, &VT[buf][cB * 8]);
    };

    // Q fragments from global (fp16)
    const size_t qrow = (size_t)bh * CTXLEN + qb * 64 + wave * 16 + lc;
    f16x8 qfr[2];
    #pragma unroll
    for (int ds = 0; ds < 2; ++ds)
        qfr[ds] = *reinterpret_cast<const f16x8*>(&qf[qrow * HDIM + ds * 32 + lg * 8]);

    const f32x4 zero4 = {0.f, 0.f, 0.f, 0.f};
    f32x4 yacc[4];
    #pragma unroll
    for (int t = 0; t < 4; ++t) yacc[t] = zero4;
    float m_i[4] = {-1e30f, -1e30f, -1e30f, -1e30f};
    float l_i[4] = {0.f, 0.f, 0.f, 0.f};

    stage(0, 0);
    __syncthreads();

    int cur = 0;
    for (int kb = 0; kb <= qb; ++kb) {
        if (kb < qb) stage(kb + 1, cur ^ 1);

        // ---- K fragments from LDS (swizzled) ----
        f16x8 kfr[4][2];
        #pragma unroll
        for (int tc = 0; tc < 4; ++tc) {
            const int rk = tc * 16 + lc;
            #pragma unroll
            for (int ds = 0; ds < 2; ++ds) {
                const int a = rk * 64 + (((ds * 4 + lg) ^ (rk & 7)) * 8);
                kfr[tc][ds] = *reinterpret_cast<const f16x8*>(&KH[cur][a]);
            }
        }

        // ---- S = Q K^T (single-term fp16) ----
        f32x4 sacc[4];
        #pragma unroll
        for (int t = 0; t < 4; ++t) sacc[t] = zero4;
        __builtin_amdgcn_s_setprio(1);
        #pragma unroll
        for (int tc = 0; tc < 4; ++tc)
            #pragma unroll
            for (int ds = 0; ds < 2; ++ds)
                sacc[tc] = mfma16f(qfr[ds], kfr[tc][ds], sacc[tc]);
        __builtin_amdgcn_s_setprio(0);

        // ---- mask + online softmax (base-2) ----
        const bool diag = (kb == qb);
        float sv[4][4];
        #pragma unroll
        for (int tc = 0; tc < 4; ++tc)
            #pragma unroll
            for (int i = 0; i < 4; ++i) {
                float u = sacc[tc][i] * SCALE_LOG2;
                if (diag && (tc * 16 + lc) > (wave * 16 + lg * 4 + i)) u = -1e30f;
                sv[tc][i] = u;
            }
        #pragma unroll
        for (int i = 0; i < 4; ++i) {
            float mx = fmaxf(fmaxf(sv[0][i], sv[1][i]), fmaxf(sv[2][i], sv[3][i]));
            mx = fmaxf(mx, __shfl_xor(mx, 1));
            mx = fmaxf(mx, __shfl_xor(mx, 2));
            mx = fmaxf(mx, __shfl_xor(mx, 4));
            mx = fmaxf(mx, __shfl_xor(mx, 8));
            const float mnew = fmaxf(m_i[i], mx);
            const float corr = fast_exp2(m_i[i] - mnew);
            float psum = 0.f;
            #pragma unroll
            for (int tc = 0; tc < 4; ++tc) {
                const float p = fast_exp2(sv[tc][i] - mnew);
                sv[tc][i] = p;
                psum += p;
            }
            psum += __shfl_xor(psum, 1);
            psum += __shfl_xor(psum, 2);
            psum += __shfl_xor(psum, 4);
            psum += __shfl_xor(psum, 8);
            l_i[i] = l_i[i] * corr + psum;
            m_i[i] = mnew;
            #pragma unroll
            for (int t = 0; t < 4; ++t) yacc[t][i] *= corr;
        }

        // ---- P -> LDS (wave-private, XOR-swizzled, fp16) ----
        #pragma unroll
        for (int tc = 0; tc < 4; ++tc)
            #pragma unroll
            for (int i = 0; i < 4; ++i) {
                const int row = lg * 4 + i;
                const int e   = tc * 16 + lc;
                const int se  = (((e >> 3) ^ (row & 7)) << 3) | (e & 7);
                Ps[wave][row][se] = f32_f16(sv[tc][i]);
            }

        // ---- y += P V ----
        f16x8 pa[2];
        #pragma unroll
        for (int ks = 0; ks < 2; ++ks) {
            const int sl = ((ks * 4 + lg) ^ (lc & 7)) << 3;
            pa[ks] = *reinterpret_cast<const f16x8*>(&Ps[wave][lc][sl]);
        }
        __builtin_amdgcn_s_setprio(1);
        #pragma unroll
        for (int t = 0; t < 4; ++t) {
            const int rv = t * 16 + lc;
            #pragma unroll
            for (int ks = 0; ks < 2; ++ks) {
                const int a = rv * 64 + (((ks * 4 + lg) ^ (rv & 7)) * 8);
                const f16x8 vf = *reinterpret_cast<const f16x8*>(&VT[cur][a]);
                yacc[t] = mfma16f(pa[ks], vf, yacc[t]);
            }
        }
        __builtin_amdgcn_s_setprio(0);

        __syncthreads();
        cur ^= 1;
    }

    float inv[4];
    #pragma unroll
    for (int i = 0; i < 4; ++i) inv[i] = 1.0f / l_i[i];
    ushort_t* yrow0 = yb + (size_t)(b * CTXLEN + qb * 64 + wave * 16 + lg * 4) * DMODEL
                      + (bh & 15) * HDIM;
    #pragma unroll
    for (int t = 0; t < 4; ++t)
        #pragma unroll
        for (int i = 0; i < 4; ++i)
            yrow0[(size_t)i * DMODEL + t * 16 + lc] = f32_f16(yacc[t][i] * inv[i]);
}

// ---------------------------------------------------------------------------
extern "C" void kernel_launch(void* const* d_in, const int* in_sizes, int n_in,
                              void* d_out, int out_size, void* d_ws, size_t ws_size,
                              hipStream_t stream) {
    const float* x      = (const float*)d_in[0];
    const float* w_qkv  = (const float*)d_in[1];
    const float* w_proj = (const float*)d_in[2];
    const float* b_proj = (const float*)d_in[3];
    float* out = (float*)d_out;

    // ws layout (bytes):
    //   wh  bf16 [3072,1024]                @ 0         ( 6,291,456)
    //   wl  bf16 [3072,1024]                @ 6291456   ( 6,291,456)
    //   xh  bf16 [4096,1024] | yb f16 reuse @ 12582912  ( 8,388,608)
    //   xl  bf16 [4096,1024] | wph f16 reuse@ 20971520  ( 8,388,608)
    //   qf  f16  [32][2048][64]             @ 29360128  ( 8,388,608)
    //   kf  f16  [32][2048][64]             @ 37748736  ( 8,388,608)
    //   vb  f16  [32][2048][64]             @ 46137344  ( 8,388,608)
    //   vt  f16  [32][64][2048]             @ 54525952  ( 8,388,608)
    char* ws = (char*)d_ws;
    ushort_t* wh  = (ushort_t*)(ws);
    ushort_t* wl  = (ushort_t*)(ws + 6291456);
    ushort_t* xh  = (ushort_t*)(ws + 12582912);
    ushort_t* xl  = (ushort_t*)(ws + 20971520);
    ushort_t* qf  = (ushort_t*)(ws + 29360128);
    ushort_t* kf  = (ushort_t*)(ws + 37748736);
    ushort_t* vb  = (ushort_t*)(ws + 46137344);
    ushort_t* vt  = (ushort_t*)(ws + 54525952);
    ushort_t* yb  = xh;
    ushort_t* wph = xl;

    const dim3 blk(256);

    split_hilo_f32<<<dim3(2048), blk, 0, stream>>>(x, xh, xl, M_TOTAL * DMODEL / 4);
    split_hilo_f32<<<dim3(2048), blk, 0, stream>>>(w_qkv, wh, wl, 3 * DMODEL * DMODEL / 4);

    // qkv GEMM A: q,k columns (N=2048), 3-term hi/lo bf16, fp16 epilogue
    gemm_mfma_nt<true, false, true><<<dim3(2048 / 128, M_TOTAL / 128), blk, 0, stream>>>(
        xh, xl, wh, wl, nullptr, nullptr, qf, kf, vb,
        M_TOTAL, 3 * DMODEL, DMODEL, 0);

    // qkv GEMM B: v columns (N=1024), single-term bf16, fp16 epilogue
    gemm_mfma_nt<false, false, true><<<dim3(1024 / 128, M_TOTAL / 128), blk, 0, stream>>>(
        xh, nullptr, wh + (size_t)2048 * DMODEL, nullptr, nullptr, nullptr,
        qf, kf, vb, M_TOTAL, 3 * DMODEL, DMODEL, 2048);

    conv_f32_f16<<<dim3(1024), blk, 0, stream>>>(w_proj, wph, DMODEL * DMODEL / 4);

    transpose_v<<<dim3(CTXLEN / 64, BATCH * NHEAD), blk, 0, stream>>>(vb, vt);

    attn_fwd4<<<dim3(1024), blk, 0, stream>>>(qf, kf, vt, yb);

    // proj: fp16 single-term (y fp16, w_proj fp16), fp32 out + bias
    gemm_mfma_nt<false, true, false><<<dim3(DMODEL / 128, M_TOTAL / 128), blk, 0, stream>>>(
        yb, nullptr, wph, nullptr, b_proj, out, nullptr, nullptr, nullptr,
        M_TOTAL, DMODEL, DMODEL, 0);
}

// Round 8
// 177.248 us; speedup vs baseline: 1.2059x; 1.0327x over previous
//
#include <hip/hip_runtime.h>
#include <hip/hip_bf16.h>

#define DMODEL 1024
#define NHEAD 16
#define HDIM 64
#define CTXLEN 2048
#define BATCH 2
#define M_TOTAL (BATCH * CTXLEN)   // 4096

typedef unsigned short ushort_t;
typedef __attribute__((ext_vector_type(8))) short bf16x8;
typedef __attribute__((ext_vector_type(8))) _Float16 f16x8;
typedef __attribute__((ext_vector_type(8))) unsigned short u16x8;
typedef __attribute__((ext_vector_type(4))) float f32x4;
typedef __attribute__((ext_vector_type(4))) unsigned short u16x4;

__device__ __forceinline__ unsigned short f32_bf16(float f) {
    unsigned u = __builtin_bit_cast(unsigned, f);
    u += 0x7FFFu + ((u >> 16) & 1u);
    return (unsigned short)(u >> 16);
}
__device__ __forceinline__ float bf16_f32(unsigned short h) {
    unsigned u = ((unsigned)h) << 16;
    return __builtin_bit_cast(float, u);
}
__device__ __forceinline__ unsigned short f32_f16(float f) {
    return __builtin_bit_cast(unsigned short, (_Float16)f);
}
__device__ __forceinline__ float fast_exp2(float x) {
    return __builtin_amdgcn_exp2f(x);
}
__device__ __forceinline__ f32x4 mfma16b(bf16x8 a, bf16x8 b, f32x4 c) {
    return __builtin_amdgcn_mfma_f32_16x16x32_bf16(a, b, c, 0, 0, 0);
}
__device__ __forceinline__ f32x4 mfma16f(f16x8 a, f16x8 b, f32x4 c) {
    return __builtin_amdgcn_mfma_f32_16x16x32_f16(a, b, c, 0, 0, 0);
}
__device__ __forceinline__ void gload_lds16(const ushort_t* g, ushort_t* l) {
    __builtin_amdgcn_global_load_lds(
        (const __attribute__((address_space(1))) void*)g,
        (__attribute__((address_space(3))) void*)l, 16, 0, 0);
}

// ---------------------------------------------------------------------------
// Elementwise converts
// ---------------------------------------------------------------------------
__global__ __launch_bounds__(256)
void split_hilo_f32(const float* __restrict__ src, ushort_t* __restrict__ h,
                    ushort_t* __restrict__ l, int n4) {
    for (int i = blockIdx.x * blockDim.x + threadIdx.x; i < n4;
         i += gridDim.x * blockDim.x) {
        const float4 v = reinterpret_cast<const float4*>(src)[i];
        const float f[4] = {v.x, v.y, v.z, v.w};
        u16x4 hi, lo;
        #pragma unroll
        for (int j = 0; j < 4; ++j) {
            const unsigned short hu = f32_bf16(f[j]);
            hi[j] = hu;
            lo[j] = f32_bf16(f[j] - bf16_f32(hu));
        }
        reinterpret_cast<u16x4*>(h)[i] = hi;
        reinterpret_cast<u16x4*>(l)[i] = lo;
    }
}

__global__ __launch_bounds__(256)
void conv_f32_f16(const float* __restrict__ src, ushort_t* __restrict__ dst, int n4) {
    for (int i = blockIdx.x * blockDim.x + threadIdx.x; i < n4;
         i += gridDim.x * blockDim.x) {
        const float4 v = reinterpret_cast<const float4*>(src)[i];
        u16x4 o;
        o[0] = f32_f16(v.x); o[1] = f32_f16(v.y);
        o[2] = f32_f16(v.z); o[3] = f32_f16(v.w);
        reinterpret_cast<u16x4*>(dst)[i] = o;
    }
}

// ---------------------------------------------------------------------------
// MFMA GEMM (NT), 128x128 tile, BK=32, 4 waves. (unchanged from R6)
// ---------------------------------------------------------------------------
template<bool SPLIT, bool F16, bool QKV_EPI>
__global__ __launch_bounds__(256)
void gemm_mfma_nt(const ushort_t* __restrict__ Ah, const ushort_t* __restrict__ Al,
                  const ushort_t* __restrict__ Bh, const ushort_t* __restrict__ Bl,
                  const float* __restrict__ bias, float* __restrict__ C,
                  ushort_t* __restrict__ qf, ushort_t* __restrict__ kf,
                  ushort_t* __restrict__ vb,
                  int M, int N, int K, int col_base) {
    constexpr int NB = SPLIT ? 4 : 2;
    constexpr int IAH = 0, IAL = 1, IBH = SPLIT ? 2 : 1, IBL = 3;
    __shared__ ushort_t lds[NB * 4096];

    const int tid  = threadIdx.x;
    const int lane = tid & 63;
    const int wave = tid >> 6;
    const int lc   = lane & 15;
    const int lg   = lane >> 4;
    const int wr   = wave >> 1;
    const int wc   = wave & 1;
    const int row0 = blockIdx.y * 128;
    const int col0 = blockIdx.x * 128;

    const int c0 = tid, c1 = 256 + tid;
    const int r0 = c0 >> 2, l0 = (c0 & 3) ^ ((c0 >> 3) & 3);
    const int r1 = c1 >> 2, l1 = (c1 & 3) ^ ((c1 >> 3) & 3);
    const size_t gaoff0 = (size_t)(row0 + r0) * K + l0 * 8;
    const size_t gaoff1 = (size_t)(row0 + r1) * K + l1 * 8;
    const size_t gboff0 = (size_t)(col0 + r0) * K + l0 * 8;
    const size_t gboff1 = (size_t)(col0 + r1) * K + l1 * 8;
    const int ld0 = c0 * 8, ld1 = c1 * 8;

    int aoff[4], boff[4];
    #pragma unroll
    for (int m = 0; m < 4; ++m) {
        const int ra = wr * 64 + m * 16 + lc;
        aoff[m] = ra * 32 + ((lg ^ ((ra >> 1) & 3)) * 8);
        const int rb = wc * 64 + m * 16 + lc;
        boff[m] = rb * 32 + ((lg ^ ((rb >> 1) & 3)) * 8);
    }

    f32x4 acc[4][4];
    const f32x4 zero4 = {0.f, 0.f, 0.f, 0.f};
    #pragma unroll
    for (int m = 0; m < 4; ++m)
        #pragma unroll
        for (int n = 0; n < 4; ++n) acc[m][n] = zero4;

    const int NT = K >> 5;

    auto stage = [&](int kt) {
        const int ko = kt * 32;
        gload_lds16(Ah + gaoff0 + ko, &lds[IAH * 4096 + ld0]);
        gload_lds16(Ah + gaoff1 + ko, &lds[IAH * 4096 + ld1]);
        if (SPLIT) {
            gload_lds16(Al + gaoff0 + ko, &lds[IAL * 4096 + ld0]);
            gload_lds16(Al + gaoff1 + ko, &lds[IAL * 4096 + ld1]);
        }
        gload_lds16(Bh + gboff0 + ko, &lds[IBH * 4096 + ld0]);
        gload_lds16(Bh + gboff1 + ko, &lds[IBH * 4096 + ld1]);
        if (SPLIT) {
            gload_lds16(Bl + gboff0 + ko, &lds[IBL * 4096 + ld0]);
            gload_lds16(Bl + gboff1 + ko, &lds[IBL * 4096 + ld1]);
        }
    };

    stage(0);
    for (int kt = 0; kt < NT; ++kt) {
        __syncthreads();
        bf16x8 fah[4], fbh[4], fal[4], fbl[4];
        #pragma unroll
        for (int m = 0; m < 4; ++m) {
            fah[m] = *reinterpret_cast<const bf16x8*>(&lds[IAH * 4096 + aoff[m]]);
            fbh[m] = *reinterpret_cast<const bf16x8*>(&lds[IBH * 4096 + boff[m]]);
            if (SPLIT) {
                fal[m] = *reinterpret_cast<const bf16x8*>(&lds[IAL * 4096 + aoff[m]]);
                fbl[m] = *reinterpret_cast<const bf16x8*>(&lds[IBL * 4096 + boff[m]]);
            }
        }
        __syncthreads();
        if (kt + 1 < NT) stage(kt + 1);
        #pragma unroll
        for (int m = 0; m < 4; ++m)
            #pragma unroll
            for (int n = 0; n < 4; ++n) {
                f32x4 t = acc[m][n];
                if (F16) {
                    t = mfma16f(__builtin_bit_cast(f16x8, fah[m]),
                                __builtin_bit_cast(f16x8, fbh[n]), t);
                } else {
                    t = mfma16b(fah[m], fbh[n], t);
                    if (SPLIT) {
                        t = mfma16b(fal[m], fbh[n], t);
                        t = mfma16b(fah[m], fbl[n], t);
                    }
                }
                acc[m][n] = t;
            }
    }

    if (!QKV_EPI) {
        #pragma unroll
        for (int m = 0; m < 4; ++m)
            #pragma unroll
            for (int i = 0; i < 4; ++i) {
                const int r = row0 + wr * 64 + m * 16 + lg * 4 + i;
                #pragma unroll
                for (int n = 0; n < 4; ++n) {
                    const int c = col0 + wc * 64 + n * 16 + lc;
                    C[(size_t)r * N + c] = acc[m][n][i] + bias[c];
                }
            }
    } else {
        #pragma unroll
        for (int m = 0; m < 4; ++m)
            #pragma unroll
            for (int i = 0; i < 4; ++i) {
                const int r = row0 + wr * 64 + m * 16 + lg * 4 + i;
                const int bb = r >> 11;
                const int t  = r & 2047;
                #pragma unroll
                for (int n = 0; n < 4; ++n) {
                    const int cg = col_base + col0 + wc * 64 + n * 16 + lc;
                    const int sec = cg >> 10;            // 0=q, 1=k, 2=v
                    const int ch  = cg & 1023;
                    const int hh  = ch >> 6;
                    const int d   = ch & 63;
                    const size_t off = (((size_t)(bb * NHEAD + hh)) * CTXLEN + t) * HDIM + d;
                    const unsigned short hv = f32_f16(acc[m][n][i]);
                    if (sec == 0)      qf[off] = hv;
                    else if (sec == 1) kf[off] = hv;
                    else               vb[off] = hv;
                }
            }
    }
}

// ---------------------------------------------------------------------------
// vb [bh][t][d] -> vt [bh][d][t], 64x64 tiles via LDS.
// ---------------------------------------------------------------------------
__global__ __launch_bounds__(256)
void transpose_v(const ushort_t* __restrict__ vb, ushort_t* __restrict__ vt) {
    __shared__ ushort_t T[64][66];
    const int tt = blockIdx.x;
    const int bh = blockIdx.y;
    const int tid = threadIdx.x;
    const int r  = tid >> 2;
    const int c0 = (tid & 3) * 16;

    const ushort_t* src = vb + ((size_t)bh * CTXLEN + tt * 64) * HDIM;
    #pragma unroll
    for (int half = 0; half < 2; ++half) {
        const u16x8 v = *reinterpret_cast<const u16x8*>(&src[(size_t)r * HDIM + c0 + half * 8]);
        #pragma unroll
        for (int j = 0; j < 8; ++j) T[r][c0 + half * 8 + j] = v[j];
    }
    __syncthreads();
    ushort_t* dst = vt + ((size_t)bh * HDIM + r) * CTXLEN + tt * 64 + c0;
    u16x8 o0, o1;
    #pragma unroll
    for (int j = 0; j < 8; ++j) { o0[j] = T[c0 + j][r]; o1[j] = T[c0 + 8 + j][r]; }
    *reinterpret_cast<u16x8*>(&dst[0]) = o0;
    *reinterpret_cast<u16x8*>(&dst[8]) = o1;
}

// ---------------------------------------------------------------------------
// Flash causal attention v5: swapped-operand fp16 MFMA.
//   S^T = mfma(K,Q)  -> lane owns ONE q-row (q = lc): softmax = reg-tree + 2 shfl
//   y^T = mfma(V^T,P)-> y[d][q=lc]: corr rescale is lane-uniform
//   QBLK=128 (4 waves x 2 m-tiles of 16 rows), KBLK=64, LDS 40KB.
// Grid 512: bh=id&31; qb = id<256 ? id>>5 : 15-((id-256)>>5)  (CU pairing -> 34
// tile-steps per CU uniformly under round-robin dispatch).
// ---------------------------------------------------------------------------
#define SCALE_LOG2 11.5415603271f   // 8 * log2(e)

__global__ __launch_bounds__(256)
void attn_fwd5(const ushort_t* __restrict__ qf, const ushort_t* __restrict__ kf,
               const ushort_t* __restrict__ vt, ushort_t* __restrict__ yb) {
    __shared__ ushort_t KH[2][4096];
    __shared__ ushort_t VT[2][4096];
    __shared__ ushort_t Ps[4][16][64];

    const int id = blockIdx.x;
    const int bh = id & 31;
    const int qb = (id < 256) ? (id >> 5) : 15 - ((id - 256) >> 5);
    const int b  = bh >> 4;
    const int h  = bh & 15;

    const int tid  = threadIdx.x;
    const int wave = tid >> 6;
    const int lane = tid & 63;
    const int lc   = lane & 15;
    const int lg   = lane >> 4;

    const ushort_t* kfb = kf + (size_t)bh * CTXLEN * HDIM;
    const ushort_t* vtb = vt + (size_t)bh * HDIM * CTXLEN;

    const int cA = tid, cB = 256 + tid;
    const int rA = cA >> 3, sgA = (cA & 7) ^ (rA & 7);
    const int rB = cB >> 3, sgB = (cB & 7) ^ (rB & 7);

    auto stage = [&](int kb, int buf) {
        const size_t koff = (size_t)(kb * 64);
        gload_lds16(kfb + (koff + rA) * HDIM + sgA * 8, &KH[buf][cA * 8]);
        gload_lds16(kfb + (koff + rB) * HDIM + sgB * 8, &KH[buf][cB * 8]);
        gload_lds16(vtb + (size_t)rA * CTXLEN + kb * 64 + sgA * 8, &VT[buf][cA * 8]);
        gload_lds16(vtb + (size_t)rB * CTXLEN + kb * 64 + sgB * 8, &VT[buf][cB * 8]);
    };

    // Q fragments (fp16): q-row = qb*128 + wave*32 + m*16 + lc
    const size_t qrow0 = (size_t)bh * CTXLEN + qb * 128 + wave * 32;
    f16x8 qfr[2][2];   // [m][ds]
    #pragma unroll
    for (int m = 0; m < 2; ++m)
        #pragma unroll
        for (int ds = 0; ds < 2; ++ds)
            qfr[m][ds] = *reinterpret_cast<const f16x8*>(
                &qf[(qrow0 + m * 16 + lc) * HDIM + ds * 32 + lg * 8]);

    const f32x4 zero4 = {0.f, 0.f, 0.f, 0.f};
    f32x4 yacc[2][4];   // [m][t]: y^T, d = t*16+lg*4+i, q = lc
    #pragma unroll
    for (int m = 0; m < 2; ++m)
        #pragma unroll
        for (int t = 0; t < 4; ++t) yacc[m][t] = zero4;
    float m_i[2] = {-1e30f, -1e30f};
    float l_i[2] = {0.f, 0.f};

    stage(0, 0);
    __syncthreads();

    const int nkb = 2 * qb + 2;
    int cur = 0;
    for (int kb = 0; kb < nkb; ++kb) {
        if (kb + 1 < nkb) stage(kb + 1, cur ^ 1);

        // ---- K fragments from LDS (swizzled) ----
        f16x8 kfr[4][2];
        #pragma unroll
        for (int tc = 0; tc < 4; ++tc) {
            const int rk = tc * 16 + lc;
            #pragma unroll
            for (int ds = 0; ds < 2; ++ds) {
                const int a = rk * 64 + (((ds * 4 + lg) ^ (rk & 7)) * 8);
                kfr[tc][ds] = *reinterpret_cast<const f16x8*>(&KH[cur][a]);
            }
        }
        // ---- V^T fragments from LDS (swizzled, shared across m) ----
        f16x8 vf[4][2];
        #pragma unroll
        for (int t = 0; t < 4; ++t) {
            const int rv = t * 16 + lc;
            #pragma unroll
            for (int ks = 0; ks < 2; ++ks) {
                const int a = rv * 64 + (((ks * 4 + lg) ^ (rv & 7)) * 8);
                vf[t][ks] = *reinterpret_cast<const f16x8*>(&VT[cur][a]);
            }
        }

        // ---- S^T = K Q^T : D[k = tc*16+lg*4+i][q = lc] ----
        f32x4 sacc[2][4];
        #pragma unroll
        for (int m = 0; m < 2; ++m)
            #pragma unroll
            for (int tc = 0; tc < 4; ++tc) sacc[m][tc] = zero4;
        __builtin_amdgcn_s_setprio(1);
        #pragma unroll
        for (int m = 0; m < 2; ++m)
            #pragma unroll
            for (int tc = 0; tc < 4; ++tc)
                #pragma unroll
                for (int ds = 0; ds < 2; ++ds)
                    sacc[m][tc] = mfma16f(kfr[tc][ds], qfr[m][ds], sacc[m][tc]);
        __builtin_amdgcn_s_setprio(0);

        const int dk = kb - 2 * qb;   // >=0 on the two diagonal tiles

        #pragma unroll
        for (int m = 0; m < 2; ++m) {
            const int q_loc = wave * 32 + m * 16 + lc;
            float p[4][4];
            #pragma unroll
            for (int tc = 0; tc < 4; ++tc)
                #pragma unroll
                for (int i = 0; i < 4; ++i) {
                    float u = sacc[m][tc][i] * SCALE_LOG2;
                    if (dk >= 0) {
                        const int k_loc = dk * 64 + tc * 16 + lg * 4 + i;
                        if (k_loc > q_loc) u = -1e30f;
                    }
                    p[tc][i] = u;
                }
            // row max: register tree + 2 shfl (across lg groups)
            float mx = p[0][0];
            #pragma unroll
            for (int tc = 0; tc < 4; ++tc)
                #pragma unroll
                for (int i = 0; i < 4; ++i) mx = fmaxf(mx, p[tc][i]);
            mx = fmaxf(mx, __shfl_xor(mx, 16));
            mx = fmaxf(mx, __shfl_xor(mx, 32));
            const float mnew = fmaxf(m_i[m], mx);
            const float corr = fast_exp2(m_i[m] - mnew);
            float psum = 0.f;
            #pragma unroll
            for (int tc = 0; tc < 4; ++tc)
                #pragma unroll
                for (int i = 0; i < 4; ++i) {
                    const float e = fast_exp2(p[tc][i] - mnew);
                    p[tc][i] = e;
                    psum += e;
                }
            psum += __shfl_xor(psum, 16);
            psum += __shfl_xor(psum, 32);
            l_i[m] = l_i[m] * corr + psum;
            m_i[m] = mnew;
            #pragma unroll
            for (int t = 0; t < 4; ++t) yacc[m][t] *= corr;

            // ---- P -> Ps (wave-private, swizzled, u16x4 chunks) ----
            #pragma unroll
            for (int tc = 0; tc < 4; ++tc) {
                const int eb = tc * 16 + lg * 4;          // k-chunk base
                const int se = ((((eb >> 3) ^ (lc & 7)) << 3) | (eb & 7));
                u16x4 pk;
                #pragma unroll
                for (int i = 0; i < 4; ++i) pk[i] = f32_f16(p[tc][i]);
                *reinterpret_cast<u16x4*>(&Ps[wave][lc][se]) = pk;
            }
            // ---- pa fragments: P[q=lc][k = ks*32+lg*8+j] ----
            f16x8 pa[2];
            #pragma unroll
            for (int ks = 0; ks < 2; ++ks) {
                const int sl = ((ks * 4 + lg) ^ (lc & 7)) << 3;
                pa[ks] = *reinterpret_cast<const f16x8*>(&Ps[wave][lc][sl]);
            }
            // ---- y^T += V^T P : D[d = t*16+lg*4+i][q = lc] ----
            __builtin_amdgcn_s_setprio(1);
            #pragma unroll
            for (int t = 0; t < 4; ++t)
                #pragma unroll
                for (int ks = 0; ks < 2; ++ks)
                    yacc[m][t] = mfma16f(vf[t][ks], pa[ks], yacc[m][t]);
            __builtin_amdgcn_s_setprio(0);
        }

        __syncthreads();
        cur ^= 1;
    }

    // ---- epilogue: lane writes its q-row (q = lc), u16x4 chunks of d ----
    #pragma unroll
    for (int m = 0; m < 2; ++m) {
        const float inv = 1.0f / l_i[m];
        ushort_t* base = yb + (size_t)(b * CTXLEN + qb * 128 + wave * 32 + m * 16 + lc) * DMODEL
                         + h * HDIM;
        #pragma unroll
        for (int t = 0; t < 4; ++t) {
            u16x4 o;
            #pragma unroll
            for (int i = 0; i < 4; ++i) o[i] = f32_f16(yacc[m][t][i] * inv);
            *reinterpret_cast<u16x4*>(&base[t * 16 + lg * 4]) = o;
        }
    }
}

// ---------------------------------------------------------------------------
extern "C" void kernel_launch(void* const* d_in, const int* in_sizes, int n_in,
                              void* d_out, int out_size, void* d_ws, size_t ws_size,
                              hipStream_t stream) {
    const float* x      = (const float*)d_in[0];
    const float* w_qkv  = (const float*)d_in[1];
    const float* w_proj = (const float*)d_in[2];
    const float* b_proj = (const float*)d_in[3];
    float* out = (float*)d_out;

    char* ws = (char*)d_ws;
    ushort_t* wh  = (ushort_t*)(ws);
    ushort_t* wl  = (ushort_t*)(ws + 6291456);
    ushort_t* xh  = (ushort_t*)(ws + 12582912);
    ushort_t* xl  = (ushort_t*)(ws + 20971520);
    ushort_t* qf  = (ushort_t*)(ws + 29360128);
    ushort_t* kf  = (ushort_t*)(ws + 37748736);
    ushort_t* vb  = (ushort_t*)(ws + 46137344);
    ushort_t* vt  = (ushort_t*)(ws + 54525952);
    ushort_t* yb  = xh;
    ushort_t* wph = xl;

    const dim3 blk(256);

    split_hilo_f32<<<dim3(2048), blk, 0, stream>>>(x, xh, xl, M_TOTAL * DMODEL / 4);
    split_hilo_f32<<<dim3(2048), blk, 0, stream>>>(w_qkv, wh, wl, 3 * DMODEL * DMODEL / 4);

    // qkv GEMM A: q,k columns (N=2048), 3-term hi/lo bf16, fp16 epilogue
    gemm_mfma_nt<true, false, true><<<dim3(2048 / 128, M_TOTAL / 128), blk, 0, stream>>>(
        xh, xl, wh, wl, nullptr, nullptr, qf, kf, vb,
        M_TOTAL, 3 * DMODEL, DMODEL, 0);

    // qkv GEMM B: v columns (N=1024), single-term bf16, fp16 epilogue
    gemm_mfma_nt<false, false, true><<<dim3(1024 / 128, M_TOTAL / 128), blk, 0, stream>>>(
        xh, nullptr, wh + (size_t)2048 * DMODEL, nullptr, nullptr, nullptr,
        qf, kf, vb, M_TOTAL, 3 * DMODEL, DMODEL, 2048);

    conv_f32_f16<<<dim3(1024), blk, 0, stream>>>(w_proj, wph, DMODEL * DMODEL / 4);

    transpose_v<<<dim3(CTXLEN / 64, BATCH * NHEAD), blk, 0, stream>>>(vb, vt);

    attn_fwd5<<<dim3(512), blk, 0, stream>>>(qf, kf, vt, yb);

    // proj: fp16 single-term, fp32 out + bias
    gemm_mfma_nt<false, true, false><<<dim3(DMODEL / 128, M_TOTAL / 128), blk, 0, stream>>>(
        yb, nullptr, wph, nullptr, b_proj, out, nullptr, nullptr, nullptr,
        M_TOTAL, DMODEL, DMODEL, 0);
}

// Round 9
// 143.412 us; speedup vs baseline: 1.4905x; 1.2359x over previous
//
#include <hip/hip_runtime.h>
#include <hip/hip_bf16.h>

#define DMODEL 1024
#define NHEAD 16
#define HDIM 64
#define CTXLEN 2048
#define BATCH 2
#define M_TOTAL (BATCH * CTXLEN)   // 4096

typedef unsigned short ushort_t;
typedef __attribute__((ext_vector_type(8))) _Float16 f16x8;
typedef __attribute__((ext_vector_type(8))) unsigned short u16x8;
typedef __attribute__((ext_vector_type(4))) float f32x4;
typedef __attribute__((ext_vector_type(4))) unsigned short u16x4;

__device__ __forceinline__ unsigned short f32_f16(float f) {
    return __builtin_bit_cast(unsigned short, (_Float16)f);
}
__device__ __forceinline__ float fast_exp2(float x) {
    return __builtin_amdgcn_exp2f(x);
}
__device__ __forceinline__ f32x4 mfma16f(f16x8 a, f16x8 b, f32x4 c) {
    return __builtin_amdgcn_mfma_f32_16x16x32_f16(a, b, c, 0, 0, 0);
}
__device__ __forceinline__ void gload_lds16(const ushort_t* g, ushort_t* l) {
    __builtin_amdgcn_global_load_lds(
        (const __attribute__((address_space(1))) void*)g,
        (__attribute__((address_space(3))) void*)l, 16, 0, 0);
}

// ---------------------------------------------------------------------------
// f32 -> f16 convert (vectorized)
// ---------------------------------------------------------------------------
__global__ __launch_bounds__(256)
void conv_f32_f16(const float* __restrict__ src, ushort_t* __restrict__ dst, int n4) {
    for (int i = blockIdx.x * blockDim.x + threadIdx.x; i < n4;
         i += gridDim.x * blockDim.x) {
        const float4 v = reinterpret_cast<const float4*>(src)[i];
        u16x4 o;
        o[0] = f32_f16(v.x); o[1] = f32_f16(v.y);
        o[2] = f32_f16(v.z); o[3] = f32_f16(v.w);
        reinterpret_cast<u16x4*>(dst)[i] = o;
    }
}

// ---------------------------------------------------------------------------
// fp16 MFMA GEMM (NT): C = A·B^T. 128x128 tile, BK=32, 4 waves.
// QKV_EPI: epilogue scatters fp16 into q/k/v [bh][t][64] arrays by column
// section; else fp32 C + bias.
// ---------------------------------------------------------------------------
template<bool QKV_EPI>
__global__ __launch_bounds__(256)
void gemm_f16_nt(const ushort_t* __restrict__ A, const ushort_t* __restrict__ B,
                 const float* __restrict__ bias, float* __restrict__ C,
                 ushort_t* __restrict__ qf, ushort_t* __restrict__ kf,
                 ushort_t* __restrict__ vb,
                 int M, int N, int K) {
    __shared__ ushort_t lds[2 * 4096];

    const int tid  = threadIdx.x;
    const int lane = tid & 63;
    const int wave = tid >> 6;
    const int lc   = lane & 15;
    const int lg   = lane >> 4;
    const int wr   = wave >> 1;
    const int wc   = wave & 1;
    const int row0 = blockIdx.y * 128;
    const int col0 = blockIdx.x * 128;

    const int c0 = tid, c1 = 256 + tid;
    const int r0 = c0 >> 2, l0 = (c0 & 3) ^ ((c0 >> 3) & 3);
    const int r1 = c1 >> 2, l1 = (c1 & 3) ^ ((c1 >> 3) & 3);
    const size_t gaoff0 = (size_t)(row0 + r0) * K + l0 * 8;
    const size_t gaoff1 = (size_t)(row0 + r1) * K + l1 * 8;
    const size_t gboff0 = (size_t)(col0 + r0) * K + l0 * 8;
    const size_t gboff1 = (size_t)(col0 + r1) * K + l1 * 8;
    const int ld0 = c0 * 8, ld1 = c1 * 8;

    int aoff[4], boff[4];
    #pragma unroll
    for (int m = 0; m < 4; ++m) {
        const int ra = wr * 64 + m * 16 + lc;
        aoff[m] = ra * 32 + ((lg ^ ((ra >> 1) & 3)) * 8);
        const int rb = wc * 64 + m * 16 + lc;
        boff[m] = rb * 32 + ((lg ^ ((rb >> 1) & 3)) * 8);
    }

    f32x4 acc[4][4];
    const f32x4 zero4 = {0.f, 0.f, 0.f, 0.f};
    #pragma unroll
    for (int m = 0; m < 4; ++m)
        #pragma unroll
        for (int n = 0; n < 4; ++n) acc[m][n] = zero4;

    const int NT = K >> 5;

    auto stage = [&](int kt) {
        const int ko = kt * 32;
        gload_lds16(A + gaoff0 + ko, &lds[ld0]);
        gload_lds16(A + gaoff1 + ko, &lds[ld1]);
        gload_lds16(B + gboff0 + ko, &lds[4096 + ld0]);
        gload_lds16(B + gboff1 + ko, &lds[4096 + ld1]);
    };

    stage(0);
    for (int kt = 0; kt < NT; ++kt) {
        __syncthreads();
        f16x8 fa[4], fb[4];
        #pragma unroll
        for (int m = 0; m < 4; ++m) {
            fa[m] = *reinterpret_cast<const f16x8*>(&lds[aoff[m]]);
            fb[m] = *reinterpret_cast<const f16x8*>(&lds[4096 + boff[m]]);
        }
        __syncthreads();
        if (kt + 1 < NT) stage(kt + 1);
        #pragma unroll
        for (int m = 0; m < 4; ++m)
            #pragma unroll
            for (int n = 0; n < 4; ++n)
                acc[m][n] = mfma16f(fa[m], fb[n], acc[m][n]);
    }

    if (!QKV_EPI) {
        #pragma unroll
        for (int m = 0; m < 4; ++m)
            #pragma unroll
            for (int i = 0; i < 4; ++i) {
                const int r = row0 + wr * 64 + m * 16 + lg * 4 + i;
                #pragma unroll
                for (int n = 0; n < 4; ++n) {
                    const int c = col0 + wc * 64 + n * 16 + lc;
                    C[(size_t)r * N + c] = acc[m][n][i] + bias[c];
                }
            }
    } else {
        #pragma unroll
        for (int m = 0; m < 4; ++m)
            #pragma unroll
            for (int i = 0; i < 4; ++i) {
                const int r = row0 + wr * 64 + m * 16 + lg * 4 + i;
                const int bb = r >> 11;
                const int t  = r & 2047;
                #pragma unroll
                for (int n = 0; n < 4; ++n) {
                    const int cg  = col0 + wc * 64 + n * 16 + lc;
                    const int sec = cg >> 10;            // 0=q, 1=k, 2=v
                    const int ch  = cg & 1023;
                    const int hh  = ch >> 6;
                    const int d   = ch & 63;
                    const size_t off = (((size_t)(bb * NHEAD + hh)) * CTXLEN + t) * HDIM + d;
                    const unsigned short hv = f32_f16(acc[m][n][i]);
                    if (sec == 0)      qf[off] = hv;
                    else if (sec == 1) kf[off] = hv;
                    else               vb[off] = hv;
                }
            }
    }
}

// ---------------------------------------------------------------------------
// vb [bh][t][d] -> vt [bh][d][t], 64x64 tiles via LDS.
// ---------------------------------------------------------------------------
__global__ __launch_bounds__(256)
void transpose_v(const ushort_t* __restrict__ vb, ushort_t* __restrict__ vt) {
    __shared__ ushort_t T[64][66];
    const int tt = blockIdx.x;
    const int bh = blockIdx.y;
    const int tid = threadIdx.x;
    const int r  = tid >> 2;
    const int c0 = (tid & 3) * 16;

    const ushort_t* src = vb + ((size_t)bh * CTXLEN + tt * 64) * HDIM;
    #pragma unroll
    for (int half = 0; half < 2; ++half) {
        const u16x8 v = *reinterpret_cast<const u16x8*>(&src[(size_t)r * HDIM + c0 + half * 8]);
        #pragma unroll
        for (int j = 0; j < 8; ++j) T[r][c0 + half * 8 + j] = v[j];
    }
    __syncthreads();
    ushort_t* dst = vt + ((size_t)bh * HDIM + r) * CTXLEN + tt * 64 + c0;
    u16x8 o0, o1;
    #pragma unroll
    for (int j = 0; j < 8; ++j) { o0[j] = T[c0 + j][r]; o1[j] = T[c0 + 8 + j][r]; }
    *reinterpret_cast<u16x8*>(&dst[0]) = o0;
    *reinterpret_cast<u16x8*>(&dst[8]) = o1;
}

// ---------------------------------------------------------------------------
// Flash causal attention v5 (unchanged from R7): swapped-operand fp16 MFMA.
// ---------------------------------------------------------------------------
#define SCALE_LOG2 11.5415603271f   // 8 * log2(e)

__global__ __launch_bounds__(256)
void attn_fwd5(const ushort_t* __restrict__ qf, const ushort_t* __restrict__ kf,
               const ushort_t* __restrict__ vt, ushort_t* __restrict__ yb) {
    __shared__ ushort_t KH[2][4096];
    __shared__ ushort_t VT[2][4096];
    __shared__ ushort_t Ps[4][16][64];

    const int id = blockIdx.x;
    const int bh = id & 31;
    const int qb = (id < 256) ? (id >> 5) : 15 - ((id - 256) >> 5);
    const int b  = bh >> 4;
    const int h  = bh & 15;

    const int tid  = threadIdx.x;
    const int wave = tid >> 6;
    const int lane = tid & 63;
    const int lc   = lane & 15;
    const int lg   = lane >> 4;

    const ushort_t* kfb = kf + (size_t)bh * CTXLEN * HDIM;
    const ushort_t* vtb = vt + (size_t)bh * HDIM * CTXLEN;

    const int cA = tid, cB = 256 + tid;
    const int rA = cA >> 3, sgA = (cA & 7) ^ (rA & 7);
    const int rB = cB >> 3, sgB = (cB & 7) ^ (rB & 7);

    auto stage = [&](int kb, int buf) {
        const size_t koff = (size_t)(kb * 64);
        gload_lds16(kfb + (koff + rA) * HDIM + sgA * 8, &KH[buf][cA * 8]);
        gload_lds16(kfb + (koff + rB) * HDIM + sgB * 8, &KH[buf][cB * 8]);
        gload_lds16(vtb + (size_t)rA * CTXLEN + kb * 64 + sgA * 8, &VT[buf][cA * 8]);
        gload_lds16(vtb + (size_t)rB * CTXLEN + kb * 64 + sgB * 8, &VT[buf][cB * 8]);
    };

    const size_t qrow0 = (size_t)bh * CTXLEN + qb * 128 + wave * 32;
    f16x8 qfr[2][2];
    #pragma unroll
    for (int m = 0; m < 2; ++m)
        #pragma unroll
        for (int ds = 0; ds < 2; ++ds)
            qfr[m][ds] = *reinterpret_cast<const f16x8*>(
                &qf[(qrow0 + m * 16 + lc) * HDIM + ds * 32 + lg * 8]);

    const f32x4 zero4 = {0.f, 0.f, 0.f, 0.f};
    f32x4 yacc[2][4];
    #pragma unroll
    for (int m = 0; m < 2; ++m)
        #pragma unroll
        for (int t = 0; t < 4; ++t) yacc[m][t] = zero4;
    float m_i[2] = {-1e30f, -1e30f};
    float l_i[2] = {0.f, 0.f};

    stage(0, 0);
    __syncthreads();

    const int nkb = 2 * qb + 2;
    int cur = 0;
    for (int kb = 0; kb < nkb; ++kb) {
        if (kb + 1 < nkb) stage(kb + 1, cur ^ 1);

        f16x8 kfr[4][2];
        #pragma unroll
        for (int tc = 0; tc < 4; ++tc) {
            const int rk = tc * 16 + lc;
            #pragma unroll
            for (int ds = 0; ds < 2; ++ds) {
                const int a = rk * 64 + (((ds * 4 + lg) ^ (rk & 7)) * 8);
                kfr[tc][ds] = *reinterpret_cast<const f16x8*>(&KH[cur][a]);
            }
        }
        f16x8 vf[4][2];
        #pragma unroll
        for (int t = 0; t < 4; ++t) {
            const int rv = t * 16 + lc;
            #pragma unroll
            for (int ks = 0; ks < 2; ++ks) {
                const int a = rv * 64 + (((ks * 4 + lg) ^ (rv & 7)) * 8);
                vf[t][ks] = *reinterpret_cast<const f16x8*>(&VT[cur][a]);
            }
        }

        f32x4 sacc[2][4];
        #pragma unroll
        for (int m = 0; m < 2; ++m)
            #pragma unroll
            for (int tc = 0; tc < 4; ++tc) sacc[m][tc] = zero4;
        __builtin_amdgcn_s_setprio(1);
        #pragma unroll
        for (int m = 0; m < 2; ++m)
            #pragma unroll
            for (int tc = 0; tc < 4; ++tc)
                #pragma unroll
                for (int ds = 0; ds < 2; ++ds)
                    sacc[m][tc] = mfma16f(kfr[tc][ds], qfr[m][ds], sacc[m][tc]);
        __builtin_amdgcn_s_setprio(0);

        const int dk = kb - 2 * qb;

        #pragma unroll
        for (int m = 0; m < 2; ++m) {
            const int q_loc = wave * 32 + m * 16 + lc;
            float p[4][4];
            #pragma unroll
            for (int tc = 0; tc < 4; ++tc)
                #pragma unroll
                for (int i = 0; i < 4; ++i) {
                    float u = sacc[m][tc][i] * SCALE_LOG2;
                    if (dk >= 0) {
                        const int k_loc = dk * 64 + tc * 16 + lg * 4 + i;
                        if (k_loc > q_loc) u = -1e30f;
                    }
                    p[tc][i] = u;
                }
            float mx = p[0][0];
            #pragma unroll
            for (int tc = 0; tc < 4; ++tc)
                #pragma unroll
                for (int i = 0; i < 4; ++i) mx = fmaxf(mx, p[tc][i]);
            mx = fmaxf(mx, __shfl_xor(mx, 16));
            mx = fmaxf(mx, __shfl_xor(mx, 32));
            const float mnew = fmaxf(m_i[m], mx);
            const float corr = fast_exp2(m_i[m] - mnew);
            float psum = 0.f;
            #pragma unroll
            for (int tc = 0; tc < 4; ++tc)
                #pragma unroll
                for (int i = 0; i < 4; ++i) {
                    const float e = fast_exp2(p[tc][i] - mnew);
                    p[tc][i] = e;
                    psum += e;
                }
            psum += __shfl_xor(psum, 16);
            psum += __shfl_xor(psum, 32);
            l_i[m] = l_i[m] * corr + psum;
            m_i[m] = mnew;
            #pragma unroll
            for (int t = 0; t < 4; ++t) yacc[m][t] *= corr;

            #pragma unroll
            for (int tc = 0; tc < 4; ++tc) {
                const int eb = tc * 16 + lg * 4;
                const int se = ((((eb >> 3) ^ (lc & 7)) << 3) | (eb & 7));
                u16x4 pk;
                #pragma unroll
                for (int i = 0; i < 4; ++i) pk[i] = f32_f16(p[tc][i]);
                *reinterpret_cast<u16x4*>(&Ps[wave][lc][se]) = pk;
            }
            f16x8 pa[2];
            #pragma unroll
            for (int ks = 0; ks < 2; ++ks) {
                const int sl = ((ks * 4 + lg) ^ (lc & 7)) << 3;
                pa[ks] = *reinterpret_cast<const f16x8*>(&Ps[wave][lc][sl]);
            }
            __builtin_amdgcn_s_setprio(1);
            #pragma unroll
            for (int t = 0; t < 4; ++t)
                #pragma unroll
                for (int ks = 0; ks < 2; ++ks)
                    yacc[m][t] = mfma16f(vf[t][ks], pa[ks], yacc[m][t]);
            __builtin_amdgcn_s_setprio(0);
        }

        __syncthreads();
        cur ^= 1;
    }

    #pragma unroll
    for (int m = 0; m < 2; ++m) {
        const float inv = 1.0f / l_i[m];
        ushort_t* base = yb + (size_t)(b * CTXLEN + qb * 128 + wave * 32 + m * 16 + lc) * DMODEL
                         + h * HDIM;
        #pragma unroll
        for (int t = 0; t < 4; ++t) {
            u16x4 o;
            #pragma unroll
            for (int i = 0; i < 4; ++i) o[i] = f32_f16(yacc[m][t][i] * inv);
            *reinterpret_cast<u16x4*>(&base[t * 16 + lg * 4]) = o;
        }
    }
}

// ---------------------------------------------------------------------------
extern "C" void kernel_launch(void* const* d_in, const int* in_sizes, int n_in,
                              void* d_out, int out_size, void* d_ws, size_t ws_size,
                              hipStream_t stream) {
    const float* x      = (const float*)d_in[0];
    const float* w_qkv  = (const float*)d_in[1];
    const float* w_proj = (const float*)d_in[2];
    const float* b_proj = (const float*)d_in[3];
    float* out = (float*)d_out;

    // ws layout (bytes):
    //   wqf f16 [3072,1024]                 @ 0          (6,291,456)
    //   wpf f16 [1024,1024]                 @ 6291456    (2,097,152)
    //   xf  f16 [4096,1024] | yb f16 reuse  @ 8388608    (8,388,608)
    //   qf  f16 [32][2048][64]              @ 16777216   (8,388,608)
    //   kf  f16 [32][2048][64]              @ 25165824   (8,388,608)
    //   vb  f16 [32][2048][64]              @ 33554432   (8,388,608)
    //   vt  f16 [32][64][2048]              @ 41943040   (8,388,608)
    char* ws = (char*)d_ws;
    ushort_t* wqf = (ushort_t*)(ws);
    ushort_t* wpf = (ushort_t*)(ws + 6291456);
    ushort_t* xf  = (ushort_t*)(ws + 8388608);
    ushort_t* qf  = (ushort_t*)(ws + 16777216);
    ushort_t* kf  = (ushort_t*)(ws + 25165824);
    ushort_t* vb  = (ushort_t*)(ws + 33554432);
    ushort_t* vt  = (ushort_t*)(ws + 41943040);
    ushort_t* yb  = xf;   // reused after qkv GEMM consumed xf

    const dim3 blk(256);

    conv_f32_f16<<<dim3(2048), blk, 0, stream>>>(x, xf, M_TOTAL * DMODEL / 4);
    conv_f32_f16<<<dim3(2048), blk, 0, stream>>>(w_qkv, wqf, 3 * DMODEL * DMODEL / 4);
    conv_f32_f16<<<dim3(1024), blk, 0, stream>>>(w_proj, wpf, DMODEL * DMODEL / 4);

    // qkv = x @ w_qkv^T, single fp16 GEMM (N=3072), epilogue scatters q/k/v
    gemm_f16_nt<true><<<dim3(3 * DMODEL / 128, M_TOTAL / 128), blk, 0, stream>>>(
        xf, wqf, nullptr, nullptr, qf, kf, vb, M_TOTAL, 3 * DMODEL, DMODEL);

    transpose_v<<<dim3(CTXLEN / 64, BATCH * NHEAD), blk, 0, stream>>>(vb, vt);

    attn_fwd5<<<dim3(512), blk, 0, stream>>>(qf, kf, vt, yb);

    // out = y @ w_proj^T + b
    gemm_f16_nt<false><<<dim3(DMODEL / 128, M_TOTAL / 128), blk, 0, stream>>>(
        yb, wpf, b_proj, out, nullptr, nullptr, nullptr, M_TOTAL, DMODEL, DMODEL);
}

// Round 10
// 127.432 us; speedup vs baseline: 1.6774x; 1.1254x over previous
//
#include <hip/hip_runtime.h>
#include <hip/hip_bf16.h>

#define DMODEL 1024
#define NHEAD 16
#define HDIM 64
#define CTXLEN 2048
#define BATCH 2
#define M_TOTAL (BATCH * CTXLEN)   // 4096

typedef unsigned short ushort_t;
typedef __attribute__((ext_vector_type(8))) _Float16 f16x8;
typedef __attribute__((ext_vector_type(8))) unsigned short u16x8;
typedef __attribute__((ext_vector_type(4))) float f32x4;
typedef __attribute__((ext_vector_type(4))) unsigned short u16x4;

__device__ __forceinline__ unsigned short f32_f16(float f) {
    return __builtin_bit_cast(unsigned short, (_Float16)f);
}
__device__ __forceinline__ float fast_exp2(float x) {
    return __builtin_amdgcn_exp2f(x);
}
__device__ __forceinline__ f32x4 mfma16f(f16x8 a, f16x8 b, f32x4 c) {
    return __builtin_amdgcn_mfma_f32_16x16x32_f16(a, b, c, 0, 0, 0);
}
__device__ __forceinline__ void gload_lds16(const ushort_t* g, ushort_t* l) {
    __builtin_amdgcn_global_load_lds(
        (const __attribute__((address_space(1))) void*)g,
        (__attribute__((address_space(3))) void*)l, 16, 0, 0);
}

// ---------------------------------------------------------------------------
// f32 -> f16 convert (vectorized)
// ---------------------------------------------------------------------------
__global__ __launch_bounds__(256)
void conv_f32_f16(const float* __restrict__ src, ushort_t* __restrict__ dst, int n4) {
    for (int i = blockIdx.x * blockDim.x + threadIdx.x; i < n4;
         i += gridDim.x * blockDim.x) {
        const float4 v = reinterpret_cast<const float4*>(src)[i];
        u16x4 o;
        o[0] = f32_f16(v.x); o[1] = f32_f16(v.y);
        o[2] = f32_f16(v.z); o[3] = f32_f16(v.w);
        reinterpret_cast<u16x4*>(dst)[i] = o;
    }
}

// ---------------------------------------------------------------------------
// fp16 MFMA GEMM (NT): C = A·B^T. 128x128 tile, BK=32, 4 waves. (unchanged)
// ---------------------------------------------------------------------------
template<bool QKV_EPI>
__global__ __launch_bounds__(256)
void gemm_f16_nt(const ushort_t* __restrict__ A, const ushort_t* __restrict__ B,
                 const float* __restrict__ bias, float* __restrict__ C,
                 ushort_t* __restrict__ qf, ushort_t* __restrict__ kf,
                 ushort_t* __restrict__ vb,
                 int M, int N, int K) {
    __shared__ ushort_t lds[2 * 4096];

    const int tid  = threadIdx.x;
    const int lane = tid & 63;
    const int wave = tid >> 6;
    const int lc   = lane & 15;
    const int lg   = lane >> 4;
    const int wr   = wave >> 1;
    const int wc   = wave & 1;
    const int row0 = blockIdx.y * 128;
    const int col0 = blockIdx.x * 128;

    const int c0 = tid, c1 = 256 + tid;
    const int r0 = c0 >> 2, l0 = (c0 & 3) ^ ((c0 >> 3) & 3);
    const int r1 = c1 >> 2, l1 = (c1 & 3) ^ ((c1 >> 3) & 3);
    const size_t gaoff0 = (size_t)(row0 + r0) * K + l0 * 8;
    const size_t gaoff1 = (size_t)(row0 + r1) * K + l1 * 8;
    const size_t gboff0 = (size_t)(col0 + r0) * K + l0 * 8;
    const size_t gboff1 = (size_t)(col0 + r1) * K + l1 * 8;
    const int ld0 = c0 * 8, ld1 = c1 * 8;

    int aoff[4], boff[4];
    #pragma unroll
    for (int m = 0; m < 4; ++m) {
        const int ra = wr * 64 + m * 16 + lc;
        aoff[m] = ra * 32 + ((lg ^ ((ra >> 1) & 3)) * 8);
        const int rb = wc * 64 + m * 16 + lc;
        boff[m] = rb * 32 + ((lg ^ ((rb >> 1) & 3)) * 8);
    }

    f32x4 acc[4][4];
    const f32x4 zero4 = {0.f, 0.f, 0.f, 0.f};
    #pragma unroll
    for (int m = 0; m < 4; ++m)
        #pragma unroll
        for (int n = 0; n < 4; ++n) acc[m][n] = zero4;

    const int NT = K >> 5;

    auto stage = [&](int kt) {
        const int ko = kt * 32;
        gload_lds16(A + gaoff0 + ko, &lds[ld0]);
        gload_lds16(A + gaoff1 + ko, &lds[ld1]);
        gload_lds16(B + gboff0 + ko, &lds[4096 + ld0]);
        gload_lds16(B + gboff1 + ko, &lds[4096 + ld1]);
    };

    stage(0);
    for (int kt = 0; kt < NT; ++kt) {
        __syncthreads();
        f16x8 fa[4], fb[4];
        #pragma unroll
        for (int m = 0; m < 4; ++m) {
            fa[m] = *reinterpret_cast<const f16x8*>(&lds[aoff[m]]);
            fb[m] = *reinterpret_cast<const f16x8*>(&lds[4096 + boff[m]]);
        }
        __syncthreads();
        if (kt + 1 < NT) stage(kt + 1);
        #pragma unroll
        for (int m = 0; m < 4; ++m)
            #pragma unroll
            for (int n = 0; n < 4; ++n)
                acc[m][n] = mfma16f(fa[m], fb[n], acc[m][n]);
    }

    if (!QKV_EPI) {
        #pragma unroll
        for (int m = 0; m < 4; ++m)
            #pragma unroll
            for (int i = 0; i < 4; ++i) {
                const int r = row0 + wr * 64 + m * 16 + lg * 4 + i;
                #pragma unroll
                for (int n = 0; n < 4; ++n) {
                    const int c = col0 + wc * 64 + n * 16 + lc;
                    C[(size_t)r * N + c] = acc[m][n][i] + bias[c];
                }
            }
    } else {
        #pragma unroll
        for (int m = 0; m < 4; ++m)
            #pragma unroll
            for (int i = 0; i < 4; ++i) {
                const int r = row0 + wr * 64 + m * 16 + lg * 4 + i;
                const int bb = r >> 11;
                const int t  = r & 2047;
                #pragma unroll
                for (int n = 0; n < 4; ++n) {
                    const int cg  = col0 + wc * 64 + n * 16 + lc;
                    const int sec = cg >> 10;            // 0=q, 1=k, 2=v
                    const int ch  = cg & 1023;
                    const int hh  = ch >> 6;
                    const int d   = ch & 63;
                    const size_t off = (((size_t)(bb * NHEAD + hh)) * CTXLEN + t) * HDIM + d;
                    const unsigned short hv = f32_f16(acc[m][n][i]);
                    if (sec == 0)      qf[off] = hv;
                    else if (sec == 1) kf[off] = hv;
                    else               vb[off] = hv;
                }
            }
    }
}

// ---------------------------------------------------------------------------
// vb [bh][t][d] -> vt [bh][d][t], 64x64 tiles via LDS.
// ---------------------------------------------------------------------------
__global__ __launch_bounds__(256)
void transpose_v(const ushort_t* __restrict__ vb, ushort_t* __restrict__ vt) {
    __shared__ ushort_t T[64][66];
    const int tt = blockIdx.x;
    const int bh = blockIdx.y;
    const int tid = threadIdx.x;
    const int r  = tid >> 2;
    const int c0 = (tid & 3) * 16;

    const ushort_t* src = vb + ((size_t)bh * CTXLEN + tt * 64) * HDIM;
    #pragma unroll
    for (int half = 0; half < 2; ++half) {
        const u16x8 v = *reinterpret_cast<const u16x8*>(&src[(size_t)r * HDIM + c0 + half * 8]);
        #pragma unroll
        for (int j = 0; j < 8; ++j) T[r][c0 + half * 8 + j] = v[j];
    }
    __syncthreads();
    ushort_t* dst = vt + ((size_t)bh * HDIM + r) * CTXLEN + tt * 64 + c0;
    u16x8 o0, o1;
    #pragma unroll
    for (int j = 0; j < 8; ++j) { o0[j] = T[c0 + j][r]; o1[j] = T[c0 + 8 + j][r]; }
    *reinterpret_cast<u16x8*>(&dst[0]) = o0;
    *reinterpret_cast<u16x8*>(&dst[8]) = o1;
}

// ---------------------------------------------------------------------------
// Flash causal attention v6: swapped-operand fp16 MFMA, QBLK=64.
// Grid 1024 = 32 bh x 32 qb -> exactly 4 blocks/CU resident (LDS 40KB),
// 16 waves/CU: 4 independent tile-step chains per CU hide each other's
// latency. Balanced map: CU c sees qraw {a,a+8,a+16,a+24}; qb = 8j +
// (j odd ? g : 7-g) makes every CU's step total exactly 66.
// Wave w owns q rows qb*64 + w*16 + lc (swapped: lane = one q row).
// ---------------------------------------------------------------------------
#define SCALE_LOG2 11.5415603271f   // 8 * log2(e)

__global__ __launch_bounds__(256)
void attn_fwd6(const ushort_t* __restrict__ qf, const ushort_t* __restrict__ kf,
               const ushort_t* __restrict__ vt, ushort_t* __restrict__ yb) {
    __shared__ ushort_t KH[2][4096];
    __shared__ ushort_t VT[2][4096];
    __shared__ ushort_t Ps[4][16][64];

    const int id   = blockIdx.x;
    const int bh   = id & 31;
    const int qraw = id >> 5;                 // 0..31
    const int jj   = qraw >> 3, g = qraw & 7;
    const int qb   = 8 * jj + ((jj & 1) ? g : 7 - g);
    const int b    = bh >> 4;
    const int h    = bh & 15;

    const int tid  = threadIdx.x;
    const int wave = tid >> 6;
    const int lane = tid & 63;
    const int lc   = lane & 15;
    const int lg   = lane >> 4;

    const ushort_t* kfb = kf + (size_t)bh * CTXLEN * HDIM;
    const ushort_t* vtb = vt + (size_t)bh * HDIM * CTXLEN;

    const int cA = tid, cB = 256 + tid;
    const int rA = cA >> 3, sgA = (cA & 7) ^ (rA & 7);
    const int rB = cB >> 3, sgB = (cB & 7) ^ (rB & 7);

    auto stage = [&](int kb, int buf) {
        const size_t koff = (size_t)(kb * 64);
        gload_lds16(kfb + (koff + rA) * HDIM + sgA * 8, &KH[buf][cA * 8]);
        gload_lds16(kfb + (koff + rB) * HDIM + sgB * 8, &KH[buf][cB * 8]);
        gload_lds16(vtb + (size_t)rA * CTXLEN + kb * 64 + sgA * 8, &VT[buf][cA * 8]);
        gload_lds16(vtb + (size_t)rB * CTXLEN + kb * 64 + sgB * 8, &VT[buf][cB * 8]);
    };

    // Q fragments: q row = qb*64 + wave*16 + lc
    const size_t qrow = (size_t)bh * CTXLEN + qb * 64 + wave * 16 + lc;
    f16x8 qfr[2];
    #pragma unroll
    for (int ds = 0; ds < 2; ++ds)
        qfr[ds] = *reinterpret_cast<const f16x8*>(&qf[qrow * HDIM + ds * 32 + lg * 8]);

    const f32x4 zero4 = {0.f, 0.f, 0.f, 0.f};
    f32x4 yacc[4];   // y^T: d = t*16+lg*4+i, q = lc
    #pragma unroll
    for (int t = 0; t < 4; ++t) yacc[t] = zero4;
    float m_i = -1e30f, l_i = 0.f;

    stage(0, 0);
    __syncthreads();

    int cur = 0;
    for (int kb = 0; kb <= qb; ++kb) {
        if (kb < qb) stage(kb + 1, cur ^ 1);

        // K fragments (swizzled)
        f16x8 kfr[4][2];
        #pragma unroll
        for (int tc = 0; tc < 4; ++tc) {
            const int rk = tc * 16 + lc;
            #pragma unroll
            for (int ds = 0; ds < 2; ++ds) {
                const int a = rk * 64 + (((ds * 4 + lg) ^ (rk & 7)) * 8);
                kfr[tc][ds] = *reinterpret_cast<const f16x8*>(&KH[cur][a]);
            }
        }
        // V^T fragments (swizzled)
        f16x8 vf[4][2];
        #pragma unroll
        for (int t = 0; t < 4; ++t) {
            const int rv = t * 16 + lc;
            #pragma unroll
            for (int ks = 0; ks < 2; ++ks) {
                const int a = rv * 64 + (((ks * 4 + lg) ^ (rv & 7)) * 8);
                vf[t][ks] = *reinterpret_cast<const f16x8*>(&VT[cur][a]);
            }
        }

        // S^T = K Q^T : D[k = tc*16+lg*4+i][q = lc]
        f32x4 sacc[4];
        #pragma unroll
        for (int tc = 0; tc < 4; ++tc) sacc[tc] = zero4;
        __builtin_amdgcn_s_setprio(1);
        #pragma unroll
        for (int tc = 0; tc < 4; ++tc)
            #pragma unroll
            for (int ds = 0; ds < 2; ++ds)
                sacc[tc] = mfma16f(kfr[tc][ds], qfr[ds], sacc[tc]);
        __builtin_amdgcn_s_setprio(0);

        const bool diag = (kb == qb);
        const int q_loc = wave * 16 + lc;
        float p[4][4];
        #pragma unroll
        for (int tc = 0; tc < 4; ++tc)
            #pragma unroll
            for (int i = 0; i < 4; ++i) {
                float u = sacc[tc][i] * SCALE_LOG2;
                if (diag && (tc * 16 + lg * 4 + i) > q_loc) u = -1e30f;
                p[tc][i] = u;
            }
        float mx = p[0][0];
        #pragma unroll
        for (int tc = 0; tc < 4; ++tc)
            #pragma unroll
            for (int i = 0; i < 4; ++i) mx = fmaxf(mx, p[tc][i]);
        mx = fmaxf(mx, __shfl_xor(mx, 16));
        mx = fmaxf(mx, __shfl_xor(mx, 32));
        const float mnew = fmaxf(m_i, mx);
        const float corr = fast_exp2(m_i - mnew);
        float psum = 0.f;
        #pragma unroll
        for (int tc = 0; tc < 4; ++tc)
            #pragma unroll
            for (int i = 0; i < 4; ++i) {
                const float e = fast_exp2(p[tc][i] - mnew);
                p[tc][i] = e;
                psum += e;
            }
        psum += __shfl_xor(psum, 16);
        psum += __shfl_xor(psum, 32);
        l_i = l_i * corr + psum;
        m_i = mnew;
        #pragma unroll
        for (int t = 0; t < 4; ++t) yacc[t] *= corr;

        // P -> Ps (wave-private, swizzled, u16x4 chunks)
        #pragma unroll
        for (int tc = 0; tc < 4; ++tc) {
            const int eb = tc * 16 + lg * 4;
            const int se = ((((eb >> 3) ^ (lc & 7)) << 3) | (eb & 7));
            u16x4 pk;
            #pragma unroll
            for (int i = 0; i < 4; ++i) pk[i] = f32_f16(p[tc][i]);
            *reinterpret_cast<u16x4*>(&Ps[wave][lc][se]) = pk;
        }
        f16x8 pa[2];
        #pragma unroll
        for (int ks = 0; ks < 2; ++ks) {
            const int sl = ((ks * 4 + lg) ^ (lc & 7)) << 3;
            pa[ks] = *reinterpret_cast<const f16x8*>(&Ps[wave][lc][sl]);
        }
        // y^T += V^T P
        __builtin_amdgcn_s_setprio(1);
        #pragma unroll
        for (int t = 0; t < 4; ++t)
            #pragma unroll
            for (int ks = 0; ks < 2; ++ks)
                yacc[t] = mfma16f(vf[t][ks], pa[ks], yacc[t]);
        __builtin_amdgcn_s_setprio(0);

        __syncthreads();
        cur ^= 1;
    }

    // epilogue: lane writes its q row, u16x4 chunks of d
    const float inv = 1.0f / l_i;
    ushort_t* base = yb + (size_t)(b * CTXLEN + qb * 64 + wave * 16 + lc) * DMODEL
                     + h * HDIM;
    #pragma unroll
    for (int t = 0; t < 4; ++t) {
        u16x4 o;
        #pragma unroll
        for (int i = 0; i < 4; ++i) o[i] = f32_f16(yacc[t][i] * inv);
        *reinterpret_cast<u16x4*>(&base[t * 16 + lg * 4]) = o;
    }
}

// ---------------------------------------------------------------------------
extern "C" void kernel_launch(void* const* d_in, const int* in_sizes, int n_in,
                              void* d_out, int out_size, void* d_ws, size_t ws_size,
                              hipStream_t stream) {
    const float* x      = (const float*)d_in[0];
    const float* w_qkv  = (const float*)d_in[1];
    const float* w_proj = (const float*)d_in[2];
    const float* b_proj = (const float*)d_in[3];
    float* out = (float*)d_out;

    // ws layout (bytes):
    //   wqf f16 [3072,1024]                 @ 0          (6,291,456)
    //   wpf f16 [1024,1024]                 @ 6291456    (2,097,152)
    //   xf  f16 [4096,1024] | yb f16 reuse  @ 8388608    (8,388,608)
    //   qf  f16 [32][2048][64]              @ 16777216   (8,388,608)
    //   kf  f16 [32][2048][64]              @ 25165824   (8,388,608)
    //   vb  f16 [32][2048][64]              @ 33554432   (8,388,608)
    //   vt  f16 [32][64][2048]              @ 41943040   (8,388,608)
    char* ws = (char*)d_ws;
    ushort_t* wqf = (ushort_t*)(ws);
    ushort_t* wpf = (ushort_t*)(ws + 6291456);
    ushort_t* xf  = (ushort_t*)(ws + 8388608);
    ushort_t* qf  = (ushort_t*)(ws + 16777216);
    ushort_t* kf  = (ushort_t*)(ws + 25165824);
    ushort_t* vb  = (ushort_t*)(ws + 33554432);
    ushort_t* vt  = (ushort_t*)(ws + 41943040);
    ushort_t* yb  = xf;   // reused after qkv GEMM consumed xf

    const dim3 blk(256);

    conv_f32_f16<<<dim3(2048), blk, 0, stream>>>(x, xf, M_TOTAL * DMODEL / 4);
    conv_f32_f16<<<dim3(2048), blk, 0, stream>>>(w_qkv, wqf, 3 * DMODEL * DMODEL / 4);
    conv_f32_f16<<<dim3(1024), blk, 0, stream>>>(w_proj, wpf, DMODEL * DMODEL / 4);

    // qkv = x @ w_qkv^T, single fp16 GEMM (N=3072), epilogue scatters q/k/v
    gemm_f16_nt<true><<<dim3(3 * DMODEL / 128, M_TOTAL / 128), blk, 0, stream>>>(
        xf, wqf, nullptr, nullptr, qf, kf, vb, M_TOTAL, 3 * DMODEL, DMODEL);

    transpose_v<<<dim3(CTXLEN / 64, BATCH * NHEAD), blk, 0, stream>>>(vb, vt);

    attn_fwd6<<<dim3(1024), blk, 0, stream>>>(qf, kf, vt, yb);

    // out = y @ w_proj^T + b
    gemm_f16_nt<false><<<dim3(DMODEL / 128, M_TOTAL / 128), blk, 0, stream>>>(
        yb, wpf, b_proj, out, nullptr, nullptr, nullptr, M_TOTAL, DMODEL, DMODEL);
}

// Round 11
// 126.934 us; speedup vs baseline: 1.6839x; 1.0039x over previous
//
#include <hip/hip_runtime.h>
#include <hip/hip_bf16.h>

#define DMODEL 1024
#define NHEAD 16
#define HDIM 64
#define CTXLEN 2048
#define BATCH 2
#define M_TOTAL (BATCH * CTXLEN)   // 4096

typedef unsigned short ushort_t;
typedef __attribute__((ext_vector_type(8))) _Float16 f16x8;
typedef __attribute__((ext_vector_type(8))) unsigned short u16x8;
typedef __attribute__((ext_vector_type(4))) float f32x4;
typedef __attribute__((ext_vector_type(4))) unsigned short u16x4;

__device__ __forceinline__ unsigned short f32_f16(float f) {
    return __builtin_bit_cast(unsigned short, (_Float16)f);
}
__device__ __forceinline__ float f16_f32(unsigned short h) {
    return (float)__builtin_bit_cast(_Float16, h);
}
__device__ __forceinline__ float fast_exp2(float x) {
    return __builtin_amdgcn_exp2f(x);
}
__device__ __forceinline__ f32x4 mfma16f(f16x8 a, f16x8 b, f32x4 c) {
    return __builtin_amdgcn_mfma_f32_16x16x32_f16(a, b, c, 0, 0, 0);
}
__device__ __forceinline__ void gload_lds16(const ushort_t* g, ushort_t* l) {
    __builtin_amdgcn_global_load_lds(
        (const __attribute__((address_space(1))) void*)g,
        (__attribute__((address_space(3))) void*)l, 16, 0, 0);
}
// units per q-tile: nu = qt/8+1; slot offset of first unit of qt within a bh
__device__ __forceinline__ int unit_off(int qt) {
    if (qt < 8)  return qt;
    if (qt < 16) return 8 + (qt - 8) * 2;
    if (qt < 24) return 24 + (qt - 16) * 3;
    return 48 + (qt - 24) * 4;
}

// ---------------------------------------------------------------------------
// f32 -> f16 convert (vectorized)
// ---------------------------------------------------------------------------
__global__ __launch_bounds__(256)
void conv_f32_f16(const float* __restrict__ src, ushort_t* __restrict__ dst, int n4) {
    for (int i = blockIdx.x * blockDim.x + threadIdx.x; i < n4;
         i += gridDim.x * blockDim.x) {
        const float4 v = reinterpret_cast<const float4*>(src)[i];
        u16x4 o;
        o[0] = f32_f16(v.x); o[1] = f32_f16(v.y);
        o[2] = f32_f16(v.z); o[3] = f32_f16(v.w);
        reinterpret_cast<u16x4*>(dst)[i] = o;
    }
}

// ---------------------------------------------------------------------------
// fp16 MFMA GEMM (NT): C = A·B^T. 128x128 tile, BK=32, 4 waves. (unchanged)
// ---------------------------------------------------------------------------
template<bool QKV_EPI>
__global__ __launch_bounds__(256)
void gemm_f16_nt(const ushort_t* __restrict__ A, const ushort_t* __restrict__ B,
                 const float* __restrict__ bias, float* __restrict__ C,
                 ushort_t* __restrict__ qf, ushort_t* __restrict__ kf,
                 ushort_t* __restrict__ vb,
                 int M, int N, int K) {
    __shared__ ushort_t lds[2 * 4096];

    const int tid  = threadIdx.x;
    const int lane = tid & 63;
    const int wave = tid >> 6;
    const int lc   = lane & 15;
    const int lg   = lane >> 4;
    const int wr   = wave >> 1;
    const int wc   = wave & 1;
    const int row0 = blockIdx.y * 128;
    const int col0 = blockIdx.x * 128;

    const int c0 = tid, c1 = 256 + tid;
    const int r0 = c0 >> 2, l0 = (c0 & 3) ^ ((c0 >> 3) & 3);
    const int r1 = c1 >> 2, l1 = (c1 & 3) ^ ((c1 >> 3) & 3);
    const size_t gaoff0 = (size_t)(row0 + r0) * K + l0 * 8;
    const size_t gaoff1 = (size_t)(row0 + r1) * K + l1 * 8;
    const size_t gboff0 = (size_t)(col0 + r0) * K + l0 * 8;
    const size_t gboff1 = (size_t)(col0 + r1) * K + l1 * 8;
    const int ld0 = c0 * 8, ld1 = c1 * 8;

    int aoff[4], boff[4];
    #pragma unroll
    for (int m = 0; m < 4; ++m) {
        const int ra = wr * 64 + m * 16 + lc;
        aoff[m] = ra * 32 + ((lg ^ ((ra >> 1) & 3)) * 8);
        const int rb = wc * 64 + m * 16 + lc;
        boff[m] = rb * 32 + ((lg ^ ((rb >> 1) & 3)) * 8);
    }

    f32x4 acc[4][4];
    const f32x4 zero4 = {0.f, 0.f, 0.f, 0.f};
    #pragma unroll
    for (int m = 0; m < 4; ++m)
        #pragma unroll
        for (int n = 0; n < 4; ++n) acc[m][n] = zero4;

    const int NT = K >> 5;

    auto stage = [&](int kt) {
        const int ko = kt * 32;
        gload_lds16(A + gaoff0 + ko, &lds[ld0]);
        gload_lds16(A + gaoff1 + ko, &lds[ld1]);
        gload_lds16(B + gboff0 + ko, &lds[4096 + ld0]);
        gload_lds16(B + gboff1 + ko, &lds[4096 + ld1]);
    };

    stage(0);
    for (int kt = 0; kt < NT; ++kt) {
        __syncthreads();
        f16x8 fa[4], fb[4];
        #pragma unroll
        for (int m = 0; m < 4; ++m) {
            fa[m] = *reinterpret_cast<const f16x8*>(&lds[aoff[m]]);
            fb[m] = *reinterpret_cast<const f16x8*>(&lds[4096 + boff[m]]);
        }
        __syncthreads();
        if (kt + 1 < NT) stage(kt + 1);
        #pragma unroll
        for (int m = 0; m < 4; ++m)
            #pragma unroll
            for (int n = 0; n < 4; ++n)
                acc[m][n] = mfma16f(fa[m], fb[n], acc[m][n]);
    }

    if (!QKV_EPI) {
        #pragma unroll
        for (int m = 0; m < 4; ++m)
            #pragma unroll
            for (int i = 0; i < 4; ++i) {
                const int r = row0 + wr * 64 + m * 16 + lg * 4 + i;
                #pragma unroll
                for (int n = 0; n < 4; ++n) {
                    const int c = col0 + wc * 64 + n * 16 + lc;
                    C[(size_t)r * N + c] = acc[m][n][i] + bias[c];
                }
            }
    } else {
        #pragma unroll
        for (int m = 0; m < 4; ++m)
            #pragma unroll
            for (int i = 0; i < 4; ++i) {
                const int r = row0 + wr * 64 + m * 16 + lg * 4 + i;
                const int bb = r >> 11;
                const int t  = r & 2047;
                #pragma unroll
                for (int n = 0; n < 4; ++n) {
                    const int cg  = col0 + wc * 64 + n * 16 + lc;
                    const int sec = cg >> 10;            // 0=q, 1=k, 2=v
                    const int ch  = cg & 1023;
                    const int hh  = ch >> 6;
                    const int d   = ch & 63;
                    const size_t off = (((size_t)(bb * NHEAD + hh)) * CTXLEN + t) * HDIM + d;
                    const unsigned short hv = f32_f16(acc[m][n][i]);
                    if (sec == 0)      qf[off] = hv;
                    else if (sec == 1) kf[off] = hv;
                    else               vb[off] = hv;
                }
            }
    }
}

// ---------------------------------------------------------------------------
// vb [bh][t][d] -> vt [bh][d][t], 64x64 tiles via LDS.
// ---------------------------------------------------------------------------
__global__ __launch_bounds__(256)
void transpose_v(const ushort_t* __restrict__ vb, ushort_t* __restrict__ vt) {
    __shared__ ushort_t T[64][66];
    const int tt = blockIdx.x;
    const int bh = blockIdx.y;
    const int tid = threadIdx.x;
    const int r  = tid >> 2;
    const int c0 = (tid & 3) * 16;

    const ushort_t* src = vb + ((size_t)bh * CTXLEN + tt * 64) * HDIM;
    #pragma unroll
    for (int half = 0; half < 2; ++half) {
        const u16x8 v = *reinterpret_cast<const u16x8*>(&src[(size_t)r * HDIM + c0 + half * 8]);
        #pragma unroll
        for (int j = 0; j < 8; ++j) T[r][c0 + half * 8 + j] = v[j];
    }
    __syncthreads();
    ushort_t* dst = vt + ((size_t)bh * HDIM + r) * CTXLEN + tt * 64 + c0;
    u16x8 o0, o1;
    #pragma unroll
    for (int j = 0; j < 8; ++j) { o0[j] = T[c0 + j][r]; o1[j] = T[c0 + 8 + j][r]; }
    *reinterpret_cast<u16x8*>(&dst[0]) = o0;
    *reinterpret_cast<u16x8*>(&dst[8]) = o1;
}

// ---------------------------------------------------------------------------
// Flash causal attention v7: split-KV units of <=8 K-tile steps.
// Grid 2560 = 80 units x 32 bh (id = u_off*32 + bh). Unit (qt, u) covers
// kb in [kb0, kb0+len), len<=8. Writes UNNORMALIZED partial y (f16) + m,l
// (f32) to slot bh*80+u_off. Oversubscribed (10 blocks/CU queue, 4 resident
// by 40KB LDS) -> hardware backfill sustains ~4 chains/CU, tail <= 8 steps.
// Inner loop identical to R9 (swapped-operand fp16 MFMA).
// ---------------------------------------------------------------------------
#define SCALE_LOG2 11.5415603271f   // 8 * log2(e)

__global__ __launch_bounds__(256)
void attn_fwd7(const ushort_t* __restrict__ qf, const ushort_t* __restrict__ kf,
               const ushort_t* __restrict__ vt,
               ushort_t* __restrict__ py, float* __restrict__ pml) {
    __shared__ ushort_t KH[2][4096];
    __shared__ ushort_t VT[2][4096];
    __shared__ ushort_t Ps[4][16][64];

    const int id    = blockIdx.x;
    const int bh    = id & 31;
    const int u_off = id >> 5;                 // 0..79
    int qt, u;
    if (u_off < 8)       { qt = u_off;                          u = 0; }
    else if (u_off < 24) { const int t = u_off - 8;  qt = 8  + (t >> 1); u = t & 1; }
    else if (u_off < 48) { const int t = u_off - 24; const int q3 = t / 3; qt = 16 + q3; u = t - q3 * 3; }
    else                 { const int t = u_off - 48; qt = 24 + (t >> 2); u = t & 3; }
    const int total = qt + 1;
    const int nu    = (qt >> 3) + 1;
    const int base  = total / nu, rem = total % nu;
    const int kb0   = u * base + (u < rem ? u : rem);
    const int len   = base + (u < rem ? 1 : 0);
    const int slot  = bh * 80 + u_off;

    const int tid  = threadIdx.x;
    const int wave = tid >> 6;
    const int lane = tid & 63;
    const int lc   = lane & 15;
    const int lg   = lane >> 4;

    const ushort_t* kfb = kf + (size_t)bh * CTXLEN * HDIM;
    const ushort_t* vtb = vt + (size_t)bh * HDIM * CTXLEN;

    const int cA = tid, cB = 256 + tid;
    const int rA = cA >> 3, sgA = (cA & 7) ^ (rA & 7);
    const int rB = cB >> 3, sgB = (cB & 7) ^ (rB & 7);

    auto stage = [&](int kb, int buf) {
        const size_t koff = (size_t)(kb * 64);
        gload_lds16(kfb + (koff + rA) * HDIM + sgA * 8, &KH[buf][cA * 8]);
        gload_lds16(kfb + (koff + rB) * HDIM + sgB * 8, &KH[buf][cB * 8]);
        gload_lds16(vtb + (size_t)rA * CTXLEN + kb * 64 + sgA * 8, &VT[buf][cA * 8]);
        gload_lds16(vtb + (size_t)rB * CTXLEN + kb * 64 + sgB * 8, &VT[buf][cB * 8]);
    };

    // Q fragments: q row = qt*64 + wave*16 + lc
    const size_t qrow = (size_t)bh * CTXLEN + qt * 64 + wave * 16 + lc;
    f16x8 qfr[2];
    #pragma unroll
    for (int ds = 0; ds < 2; ++ds)
        qfr[ds] = *reinterpret_cast<const f16x8*>(&qf[qrow * HDIM + ds * 32 + lg * 8]);

    const f32x4 zero4 = {0.f, 0.f, 0.f, 0.f};
    f32x4 yacc[4];   // y^T: d = t*16+lg*4+i, q = lc
    #pragma unroll
    for (int t = 0; t < 4; ++t) yacc[t] = zero4;
    float m_i = -1e30f, l_i = 0.f;

    stage(kb0, 0);
    __syncthreads();

    int cur = 0;
    for (int s = 0; s < len; ++s) {
        const int kb = kb0 + s;
        if (s + 1 < len) stage(kb + 1, cur ^ 1);

        f16x8 kfr[4][2];
        #pragma unroll
        for (int tc = 0; tc < 4; ++tc) {
            const int rk = tc * 16 + lc;
            #pragma unroll
            for (int ds = 0; ds < 2; ++ds) {
                const int a = rk * 64 + (((ds * 4 + lg) ^ (rk & 7)) * 8);
                kfr[tc][ds] = *reinterpret_cast<const f16x8*>(&KH[cur][a]);
            }
        }
        f16x8 vf[4][2];
        #pragma unroll
        for (int t = 0; t < 4; ++t) {
            const int rv = t * 16 + lc;
            #pragma unroll
            for (int ks = 0; ks < 2; ++ks) {
                const int a = rv * 64 + (((ks * 4 + lg) ^ (rv & 7)) * 8);
                vf[t][ks] = *reinterpret_cast<const f16x8*>(&VT[cur][a]);
            }
        }

        // S^T = K Q^T
        f32x4 sacc[4];
        #pragma unroll
        for (int tc = 0; tc < 4; ++tc) sacc[tc] = zero4;
        __builtin_amdgcn_s_setprio(1);
        #pragma unroll
        for (int tc = 0; tc < 4; ++tc)
            #pragma unroll
            for (int ds = 0; ds < 2; ++ds)
                sacc[tc] = mfma16f(kfr[tc][ds], qfr[ds], sacc[tc]);
        __builtin_amdgcn_s_setprio(0);

        const bool diag = (kb == qt);
        const int q_loc = wave * 16 + lc;
        float p[4][4];
        #pragma unroll
        for (int tc = 0; tc < 4; ++tc)
            #pragma unroll
            for (int i = 0; i < 4; ++i) {
                float uu = sacc[tc][i] * SCALE_LOG2;
                if (diag && (tc * 16 + lg * 4 + i) > q_loc) uu = -1e30f;
                p[tc][i] = uu;
            }
        float mx = p[0][0];
        #pragma unroll
        for (int tc = 0; tc < 4; ++tc)
            #pragma unroll
            for (int i = 0; i < 4; ++i) mx = fmaxf(mx, p[tc][i]);
        mx = fmaxf(mx, __shfl_xor(mx, 16));
        mx = fmaxf(mx, __shfl_xor(mx, 32));
        const float mnew = fmaxf(m_i, mx);
        const float corr = fast_exp2(m_i - mnew);
        float psum = 0.f;
        #pragma unroll
        for (int tc = 0; tc < 4; ++tc)
            #pragma unroll
            for (int i = 0; i < 4; ++i) {
                const float e = fast_exp2(p[tc][i] - mnew);
                p[tc][i] = e;
                psum += e;
            }
        psum += __shfl_xor(psum, 16);
        psum += __shfl_xor(psum, 32);
        l_i = l_i * corr + psum;
        m_i = mnew;
        #pragma unroll
        for (int t = 0; t < 4; ++t) yacc[t] *= corr;

        #pragma unroll
        for (int tc = 0; tc < 4; ++tc) {
            const int eb = tc * 16 + lg * 4;
            const int se = ((((eb >> 3) ^ (lc & 7)) << 3) | (eb & 7));
            u16x4 pk;
            #pragma unroll
            for (int i = 0; i < 4; ++i) pk[i] = f32_f16(p[tc][i]);
            *reinterpret_cast<u16x4*>(&Ps[wave][lc][se]) = pk;
        }
        f16x8 pa[2];
        #pragma unroll
        for (int ks = 0; ks < 2; ++ks) {
            const int sl = ((ks * 4 + lg) ^ (lc & 7)) << 3;
            pa[ks] = *reinterpret_cast<const f16x8*>(&Ps[wave][lc][sl]);
        }
        __builtin_amdgcn_s_setprio(1);
        #pragma unroll
        for (int t = 0; t < 4; ++t)
            #pragma unroll
            for (int ks = 0; ks < 2; ++ks)
                yacc[t] = mfma16f(vf[t][ks], pa[ks], yacc[t]);
        __builtin_amdgcn_s_setprio(0);

        __syncthreads();
        cur ^= 1;
    }

    // partial epilogue: unnormalized y (f16) + m,l (f32)
    const int row = wave * 16 + lc;
    ushort_t* prow = py + ((size_t)slot * 64 + row) * 64;
    #pragma unroll
    for (int t = 0; t < 4; ++t) {
        u16x4 o;
        #pragma unroll
        for (int i = 0; i < 4; ++i) o[i] = f32_f16(yacc[t][i]);
        *reinterpret_cast<u16x4*>(&prow[t * 16 + lg * 4]) = o;
    }
    if (lg == 0) {
        pml[(size_t)slot * 128 + row]      = m_i;
        pml[(size_t)slot * 128 + 64 + row] = l_i;
    }
}

// ---------------------------------------------------------------------------
// Merge split-KV partials: per (bh, qt) combine nu units -> yb f16.
// Grid 1024 = bh*32+qt, 256 threads: row = tid/4, d-chunk = (tid%4)*16.
// ---------------------------------------------------------------------------
__global__ __launch_bounds__(256)
void merge_attn(const ushort_t* __restrict__ py, const float* __restrict__ pml,
                ushort_t* __restrict__ yb) {
    const int bid = blockIdx.x;
    const int bh  = bid >> 5;
    const int qt  = bid & 31;
    const int b   = bh >> 4;
    const int h   = bh & 15;
    const int tid = threadIdx.x;
    const int row = tid >> 2;
    const int d0  = (tid & 3) * 16;

    const int nu    = (qt >> 3) + 1;
    const int sbase = bh * 80 + unit_off(qt);

    float mu[4], lu[4];
    float M = -1e30f;
    #pragma unroll
    for (int u = 0; u < 4; ++u) {
        if (u < nu) {
            mu[u] = pml[(size_t)(sbase + u) * 128 + row];
            lu[u] = pml[(size_t)(sbase + u) * 128 + 64 + row];
            M = fmaxf(M, mu[u]);
        } else { mu[u] = -1e30f; lu[u] = 0.f; }
    }
    float w[4], ltot = 0.f;
    #pragma unroll
    for (int u = 0; u < 4; ++u) {
        w[u] = (u < nu) ? fast_exp2(mu[u] - M) : 0.f;
        ltot += w[u] * lu[u];
    }

    float y[16];
    #pragma unroll
    for (int j = 0; j < 16; ++j) y[j] = 0.f;
    #pragma unroll
    for (int u = 0; u < 4; ++u) {
        if (u < nu) {
            const ushort_t* pr = py + ((size_t)(sbase + u) * 64 + row) * 64 + d0;
            const u16x8 a = *reinterpret_cast<const u16x8*>(&pr[0]);
            const u16x8 c = *reinterpret_cast<const u16x8*>(&pr[8]);
            #pragma unroll
            for (int j = 0; j < 8; ++j) {
                y[j]     += w[u] * f16_f32(a[j]);
                y[8 + j] += w[u] * f16_f32(c[j]);
            }
        }
    }
    const float inv = 1.0f / ltot;
    ushort_t* dst = yb + (size_t)(b * CTXLEN + qt * 64 + row) * DMODEL + h * HDIM + d0;
    u16x8 o0, o1;
    #pragma unroll
    for (int j = 0; j < 8; ++j) {
        o0[j] = f32_f16(y[j] * inv);
        o1[j] = f32_f16(y[8 + j] * inv);
    }
    *reinterpret_cast<u16x8*>(&dst[0]) = o0;
    *reinterpret_cast<u16x8*>(&dst[8]) = o1;
}

// ---------------------------------------------------------------------------
extern "C" void kernel_launch(void* const* d_in, const int* in_sizes, int n_in,
                              void* d_out, int out_size, void* d_ws, size_t ws_size,
                              hipStream_t stream) {
    const float* x      = (const float*)d_in[0];
    const float* w_qkv  = (const float*)d_in[1];
    const float* w_proj = (const float*)d_in[2];
    const float* b_proj = (const float*)d_in[3];
    float* out = (float*)d_out;

    // ws layout (bytes):
    //   wqf f16 [3072,1024]                 @ 0          (6,291,456)
    //   wpf f16 [1024,1024]                 @ 6291456    (2,097,152)
    //   xf  f16 [4096,1024] | yb f16 reuse  @ 8388608    (8,388,608)
    //   qf  f16 [32][2048][64]              @ 16777216   (8,388,608)
    //   kf  f16 [32][2048][64]              @ 25165824   (8,388,608)
    //   vb  f16 [32][2048][64]              @ 33554432   (8,388,608)
    //   vt  f16 [32][64][2048]              @ 41943040   (8,388,608)
    //   py  f16 [2560][64][64]              @ 50331648   (20,971,520)
    //   pml f32 [2560][128]                 @ 71303168   ( 1,310,720)
    char* ws = (char*)d_ws;
    ushort_t* wqf = (ushort_t*)(ws);
    ushort_t* wpf = (ushort_t*)(ws + 6291456);
    ushort_t* xf  = (ushort_t*)(ws + 8388608);
    ushort_t* qf  = (ushort_t*)(ws + 16777216);
    ushort_t* kf  = (ushort_t*)(ws + 25165824);
    ushort_t* vb  = (ushort_t*)(ws + 33554432);
    ushort_t* vt  = (ushort_t*)(ws + 41943040);
    ushort_t* py  = (ushort_t*)(ws + 50331648);
    float*    pml = (float*)   (ws + 71303168);
    ushort_t* yb  = xf;   // reused after qkv GEMM consumed xf

    const dim3 blk(256);

    conv_f32_f16<<<dim3(2048), blk, 0, stream>>>(x, xf, M_TOTAL * DMODEL / 4);
    conv_f32_f16<<<dim3(2048), blk, 0, stream>>>(w_qkv, wqf, 3 * DMODEL * DMODEL / 4);
    conv_f32_f16<<<dim3(1024), blk, 0, stream>>>(w_proj, wpf, DMODEL * DMODEL / 4);

    // qkv = x @ w_qkv^T, single fp16 GEMM (N=3072), epilogue scatters q/k/v
    gemm_f16_nt<true><<<dim3(3 * DMODEL / 128, M_TOTAL / 128), blk, 0, stream>>>(
        xf, wqf, nullptr, nullptr, qf, kf, vb, M_TOTAL, 3 * DMODEL, DMODEL);

    transpose_v<<<dim3(CTXLEN / 64, BATCH * NHEAD), blk, 0, stream>>>(vb, vt);

    // split-KV attention units + merge
    attn_fwd7<<<dim3(2560), blk, 0, stream>>>(qf, kf, vt, py, pml);
    merge_attn<<<dim3(1024), blk, 0, stream>>>(py, pml, yb);

    // out = y @ w_proj^T + b
    gemm_f16_nt<false><<<dim3(DMODEL / 128, M_TOTAL / 128), blk, 0, stream>>>(
        yb, wpf, b_proj, out, nullptr, nullptr, nullptr, M_TOTAL, DMODEL, DMODEL);
}